// Round 1
// baseline (1581.993 us; speedup 1.0000x reference)
//
#include <hip/hip_runtime.h>

#define N_NODES 50000
#define N_EDGES 800000
#define IN_DIM  128
#define IN_CH   64
#define HIDDEN  64
#define OUT_CH  128
#define NUM_CLS 16
#define NUM_G   512

// ---------------- stage1: h0 = x @ w1 + b1   [N,128]@[128,64] ----------------
__global__ __launch_bounds__(256) void k_stage1(const float* __restrict__ x,
    const float* __restrict__ w, const float* __restrict__ b,
    float* __restrict__ h0) {
  unsigned t = blockIdx.x * 256u + threadIdx.x;
  unsigned row = t >> 6;      // 64 cols
  unsigned col = t & 63u;
  if (row >= N_NODES) return;
  const float* xr = x + (size_t)row * IN_DIM;
  float s = b[col];
#pragma unroll 8
  for (int k = 0; k < IN_DIM; ++k)
    s = fmaf(xr[k], w[k * IN_CH + col], s);
  h0[(size_t)row * IN_CH + col] = s;
}

// ---------------- edge scatter-add: agg[dst] += h[src] ----------------
template <int D>
__global__ __launch_bounds__(256) void k_scatter(const float* __restrict__ h,
    const int* __restrict__ src, const int* __restrict__ dst,
    float* __restrict__ agg) {
  unsigned t = blockIdx.x * 256u + threadIdx.x;
  unsigned e = t / (unsigned)D;   // D is pow2 -> shift
  unsigned f = t & (unsigned)(D - 1);
  if (e >= N_EDGES) return;
  int s = src[e];
  int d = dst[e];
  unsafeAtomicAdd(&agg[(size_t)d * D + f], h[(size_t)s * D + f]);
}

// ---------------- combine: out = relu(agg@relw + relb + h@rootw) ----------------
template <int DIN, int DOUT>
__global__ __launch_bounds__(256) void k_combine(const float* __restrict__ agg,
    const float* __restrict__ h, const float* __restrict__ relw,
    const float* __restrict__ relb, const float* __restrict__ rootw,
    float* __restrict__ out) {
  unsigned t = blockIdx.x * 256u + threadIdx.x;
  unsigned row = t / (unsigned)DOUT;
  unsigned col = t % (unsigned)DOUT;
  if (row >= N_NODES) return;
  const float* ar = agg + (size_t)row * DIN;
  const float* hr = h + (size_t)row * DIN;
  float s = relb[col];
#pragma unroll 8
  for (int k = 0; k < DIN; ++k) {
    s = fmaf(ar[k], relw[k * DOUT + col], s);
    s = fmaf(hr[k], rootw[k * DOUT + col], s);
  }
  out[(size_t)row * DOUT + col] = fmaxf(s, 0.0f);
}

// ---------------- pooling ----------------
__global__ __launch_bounds__(256) void k_pool(const float* __restrict__ h3,
    const int* __restrict__ batch, float* __restrict__ sums) {
  unsigned t = blockIdx.x * 256u + threadIdx.x;
  unsigned n = t >> 7;       // OUT_CH = 128
  unsigned f = t & 127u;
  if (n >= N_NODES) return;
  int g = batch[n];
  unsafeAtomicAdd(&sums[(size_t)g * OUT_CH + f], h3[(size_t)n * OUT_CH + f]);
}

__global__ __launch_bounds__(256) void k_count(const int* __restrict__ batch,
    float* __restrict__ cnt) {
  unsigned n = blockIdx.x * 256u + threadIdx.x;
  if (n >= N_NODES) return;
  unsafeAtomicAdd(&cnt[batch[n]], 1.0f);
}

// ---------------- head: out = (sums/cnt) @ lin_w + lin_b ----------------
__global__ __launch_bounds__(256) void k_head(const float* __restrict__ sums,
    const float* __restrict__ cnt, const float* __restrict__ lw,
    const float* __restrict__ lb, float* __restrict__ out) {
  unsigned t = blockIdx.x * 256u + threadIdx.x;
  if (t >= NUM_G * NUM_CLS) return;
  unsigned g = t / NUM_CLS;
  unsigned c = t % NUM_CLS;
  float inv = 1.0f / fmaxf(cnt[g], 1.0f);
  float s = lb[c];
#pragma unroll
  for (int k = 0; k < OUT_CH; ++k)
    s = fmaf(sums[(size_t)g * OUT_CH + k] * inv, lw[k * NUM_CLS + c], s);
  out[t] = s;
}

extern "C" void kernel_launch(void* const* d_in, const int* in_sizes, int n_in,
                              void* d_out, int out_size, void* d_ws, size_t ws_size,
                              hipStream_t stream) {
  const float* x      = (const float*)d_in[0];
  const int*   ei     = (const int*)d_in[1];
  const int*   batch  = (const int*)d_in[2];
  // d_in[3] = num_graphs scalar (constant 512, baked in)
  const float* w1     = (const float*)d_in[4];
  const float* b1     = (const float*)d_in[5];
  const float* rel1w  = (const float*)d_in[6];
  const float* rel1b  = (const float*)d_in[7];
  const float* root1w = (const float*)d_in[8];
  const float* rel2w  = (const float*)d_in[9];
  const float* rel2b  = (const float*)d_in[10];
  const float* root2w = (const float*)d_in[11];
  const float* rel3w  = (const float*)d_in[12];
  const float* rel3b  = (const float*)d_in[13];
  const float* root3w = (const float*)d_in[14];
  const float* linw   = (const float*)d_in[15];
  const float* linb   = (const float*)d_in[16];
  const int* src = ei;
  const int* dst = ei + N_EDGES;
  float* out = (float*)d_out;

  float* P = (float*)d_ws;                       // [N,128]
  float* Q = P + (size_t)N_NODES * 128;          // [N,128]
  float* R = Q + (size_t)N_NODES * 128;          // [N,128]
  float* S = R + (size_t)N_NODES * 128;          // [G,128] pooled sums
  float* C = S + (size_t)NUM_G * OUT_CH;         // [G] counts

  // 1. h0 = x@w1 + b1 -> P[:, :64]
  k_stage1<<<(N_NODES * 64 + 255) / 256, 256, 0, stream>>>(x, w1, b1, P);

  // 2. agg1 = scatter(h0) -> Q
  hipMemsetAsync(Q, 0, (size_t)N_NODES * 64 * sizeof(float), stream);
  k_scatter<64><<<(N_EDGES * 64u + 255u) / 256u, 256, 0, stream>>>(P, src, dst, Q);

  // 3. h1 = relu(agg1@rel1 + b + h0@root1) -> R
  k_combine<64, 64><<<(N_NODES * 64 + 255) / 256, 256, 0, stream>>>(
      Q, P, rel1w, rel1b, root1w, R);

  // 4. agg2 = scatter(h1) -> P
  hipMemsetAsync(P, 0, (size_t)N_NODES * 64 * sizeof(float), stream);
  k_scatter<64><<<(N_EDGES * 64u + 255u) / 256u, 256, 0, stream>>>(R, src, dst, P);

  // 5. h2 = relu(agg2@rel2 + b + h1@root2) -> Q  [N,128]
  k_combine<64, 128><<<(N_NODES * 128 + 255) / 256, 256, 0, stream>>>(
      P, R, rel2w, rel2b, root2w, Q);

  // 6. agg3 = scatter(h2) -> R  [N,128]
  hipMemsetAsync(R, 0, (size_t)N_NODES * 128 * sizeof(float), stream);
  k_scatter<128><<<(N_EDGES * 128u + 255u) / 256u, 256, 0, stream>>>(Q, src, dst, R);

  // 7. h3 = relu(agg3@rel3 + b + h2@root3) -> P  [N,128]
  k_combine<128, 128><<<(N_NODES * 128 + 255) / 256, 256, 0, stream>>>(
      R, Q, rel3w, rel3b, root3w, P);

  // 8. global mean pool
  hipMemsetAsync(S, 0, ((size_t)NUM_G * OUT_CH + NUM_G) * sizeof(float), stream);
  k_pool<<<(N_NODES * 128 + 255) / 256, 256, 0, stream>>>(P, batch, S);
  k_count<<<(N_NODES + 255) / 256, 256, 0, stream>>>(batch, C);

  // 9. head
  k_head<<<(NUM_G * NUM_CLS + 255) / 256, 256, 0, stream>>>(S, C, linw, linb, out);
}

// Round 2
// 1017.819 us; speedup vs baseline: 1.5543x; 1.5543x over previous
//
#include <hip/hip_runtime.h>

#define N_NODES 50000
#define N_EDGES 800000
#define IN_DIM  128
#define IN_CH   64
#define HIDDEN  64
#define OUT_CH  128
#define NUM_CLS 16
#define NUM_G   512

// ============ register-tiled GEMM: out = [relu](A@Wa [+ H@Wh] + bias) ============
// Block: 256 threads. Each thread: TM=4 rows x TN=4 cols of output.
// A/H tiles staged in LDS (stride padded +4 -> worst 2-way bank alias = free).
// Weights streamed as float4 from global (L1-resident per block).
template <int DIN, int DOUT, bool HAS_ROOT, bool RELU>
__global__ __launch_bounds__(256) void k_gemm(
    const float* __restrict__ A, const float* __restrict__ H,
    const float* __restrict__ Wa, const float* __restrict__ Wh,
    const float* __restrict__ bias, float* __restrict__ out) {
  constexpr int TM = 4, TN = 4;
  constexpr int CG = DOUT / TN;     // threads covering one row's cols
  constexpr int RG = 256 / CG;      // row groups per block
  constexpr int RPB = RG * TM;      // rows per block (64 or 32)
  constexpr int LDA = DIN + 4;      // padded LDS stride (float4-aligned)

  __shared__ float sA[RPB * LDA];
  __shared__ float sH[HAS_ROOT ? RPB * LDA : 4];

  const int tid = threadIdx.x;
  const int row0 = blockIdx.x * RPB;

  // ---- stage tile(s) into LDS, float4 coalesced ----
  constexpr int NF4 = RPB * DIN / 4;
#pragma unroll
  for (int i = tid; i < NF4; i += 256) {
    int flat = i * 4;
    int r = flat / DIN;
    int k = flat - r * DIN;
    int grow = row0 + r;
    float4 va = make_float4(0.f, 0.f, 0.f, 0.f);
    float4 vh = make_float4(0.f, 0.f, 0.f, 0.f);
    if (grow < N_NODES) {
      va = *(const float4*)&A[(size_t)grow * DIN + k];
      if constexpr (HAS_ROOT) vh = *(const float4*)&H[(size_t)grow * DIN + k];
    }
    *(float4*)&sA[r * LDA + k] = va;
    if constexpr (HAS_ROOT) *(float4*)&sH[r * LDA + k] = vh;
  }
  __syncthreads();

  const int cg = tid % CG;
  const int rg = tid / CG;
  const int col0 = cg * TN;
  const int rbase = rg * TM;

  float acc[TM][TN];
#pragma unroll
  for (int i = 0; i < TM; ++i)
#pragma unroll
    for (int j = 0; j < TN; ++j) acc[i][j] = 0.f;

#pragma unroll 4
  for (int k = 0; k < DIN; ++k) {
    float4 wa = *(const float4*)&Wa[k * DOUT + col0];
    float4 wh;
    if constexpr (HAS_ROOT) wh = *(const float4*)&Wh[k * DOUT + col0];
#pragma unroll
    for (int i = 0; i < TM; ++i) {
      float a = sA[(rbase + i) * LDA + k];
      acc[i][0] = fmaf(a, wa.x, acc[i][0]);
      acc[i][1] = fmaf(a, wa.y, acc[i][1]);
      acc[i][2] = fmaf(a, wa.z, acc[i][2]);
      acc[i][3] = fmaf(a, wa.w, acc[i][3]);
      if constexpr (HAS_ROOT) {
        float hh = sH[(rbase + i) * LDA + k];
        acc[i][0] = fmaf(hh, wh.x, acc[i][0]);
        acc[i][1] = fmaf(hh, wh.y, acc[i][1]);
        acc[i][2] = fmaf(hh, wh.z, acc[i][2]);
        acc[i][3] = fmaf(hh, wh.w, acc[i][3]);
      }
    }
  }

  float4 bv = *(const float4*)&bias[col0];
#pragma unroll
  for (int i = 0; i < TM; ++i) {
    int grow = row0 + rbase + i;
    if (grow < N_NODES) {
      float4 o;
      o.x = acc[i][0] + bv.x;
      o.y = acc[i][1] + bv.y;
      o.z = acc[i][2] + bv.z;
      o.w = acc[i][3] + bv.w;
      if constexpr (RELU) {
        o.x = fmaxf(o.x, 0.f); o.y = fmaxf(o.y, 0.f);
        o.z = fmaxf(o.z, 0.f); o.w = fmaxf(o.w, 0.f);
      }
      *(float4*)&out[(size_t)grow * DOUT + col0] = o;
    }
  }
}

// ---------------- edge scatter-add: agg[dst] += h[src] ----------------
template <int D>
__global__ __launch_bounds__(256) void k_scatter(const float* __restrict__ h,
    const int* __restrict__ src, const int* __restrict__ dst,
    float* __restrict__ agg) {
  unsigned t = blockIdx.x * 256u + threadIdx.x;
  unsigned e = t / (unsigned)D;
  unsigned f = t & (unsigned)(D - 1);
  if (e >= N_EDGES) return;
  int s = src[e];
  int d = dst[e];
  unsafeAtomicAdd(&agg[(size_t)d * D + f], h[(size_t)s * D + f]);
}

// ---------------- pooling ----------------
__global__ __launch_bounds__(256) void k_pool(const float* __restrict__ h3,
    const int* __restrict__ batch, float* __restrict__ sums) {
  unsigned t = blockIdx.x * 256u + threadIdx.x;
  unsigned n = t >> 7;
  unsigned f = t & 127u;
  if (n >= N_NODES) return;
  int g = batch[n];
  unsafeAtomicAdd(&sums[(size_t)g * OUT_CH + f], h3[(size_t)n * OUT_CH + f]);
}

__global__ __launch_bounds__(256) void k_count(const int* __restrict__ batch,
    float* __restrict__ cnt) {
  unsigned n = blockIdx.x * 256u + threadIdx.x;
  if (n >= N_NODES) return;
  unsafeAtomicAdd(&cnt[batch[n]], 1.0f);
}

// ---------------- head: out = (sums/cnt) @ lin_w + lin_b ----------------
__global__ __launch_bounds__(256) void k_head(const float* __restrict__ sums,
    const float* __restrict__ cnt, const float* __restrict__ lw,
    const float* __restrict__ lb, float* __restrict__ out) {
  unsigned t = blockIdx.x * 256u + threadIdx.x;
  if (t >= NUM_G * NUM_CLS) return;
  unsigned g = t / NUM_CLS;
  unsigned c = t % NUM_CLS;
  float inv = 1.0f / fmaxf(cnt[g], 1.0f);
  float s = lb[c];
#pragma unroll
  for (int k = 0; k < OUT_CH; ++k)
    s = fmaf(sums[(size_t)g * OUT_CH + k] * inv, lw[k * NUM_CLS + c], s);
  out[t] = s;
}

extern "C" void kernel_launch(void* const* d_in, const int* in_sizes, int n_in,
                              void* d_out, int out_size, void* d_ws, size_t ws_size,
                              hipStream_t stream) {
  const float* x      = (const float*)d_in[0];
  const int*   ei     = (const int*)d_in[1];
  const int*   batch  = (const int*)d_in[2];
  const float* w1     = (const float*)d_in[4];
  const float* b1     = (const float*)d_in[5];
  const float* rel1w  = (const float*)d_in[6];
  const float* rel1b  = (const float*)d_in[7];
  const float* root1w = (const float*)d_in[8];
  const float* rel2w  = (const float*)d_in[9];
  const float* rel2b  = (const float*)d_in[10];
  const float* root2w = (const float*)d_in[11];
  const float* rel3w  = (const float*)d_in[12];
  const float* rel3b  = (const float*)d_in[13];
  const float* root3w = (const float*)d_in[14];
  const float* linw   = (const float*)d_in[15];
  const float* linb   = (const float*)d_in[16];
  const int* src = ei;
  const int* dst = ei + N_EDGES;
  float* out = (float*)d_out;

  float* P = (float*)d_ws;                       // [N,128]
  float* Q = P + (size_t)N_NODES * 128;          // [N,128]
  float* R = Q + (size_t)N_NODES * 128;          // [N,128]
  float* S = R + (size_t)N_NODES * 128;          // [G,128] pooled sums
  float* C = S + (size_t)NUM_G * OUT_CH;         // [G] counts

  // 1. h0 = x@w1 + b1 -> P   (RPB=64)
  k_gemm<IN_DIM, IN_CH, false, false><<<(N_NODES + 63) / 64, 256, 0, stream>>>(
      x, nullptr, w1, nullptr, b1, P);

  // 2. agg1 = scatter(h0) -> Q
  hipMemsetAsync(Q, 0, (size_t)N_NODES * 64 * sizeof(float), stream);
  k_scatter<64><<<(N_EDGES * 64u + 255u) / 256u, 256, 0, stream>>>(P, src, dst, Q);

  // 3. h1 = relu(agg1@rel1 + b + h0@root1) -> R   (RPB=64)
  k_gemm<IN_CH, HIDDEN, true, true><<<(N_NODES + 63) / 64, 256, 0, stream>>>(
      Q, P, rel1w, root1w, rel1b, R);

  // 4. agg2 = scatter(h1) -> P
  hipMemsetAsync(P, 0, (size_t)N_NODES * 64 * sizeof(float), stream);
  k_scatter<64><<<(N_EDGES * 64u + 255u) / 256u, 256, 0, stream>>>(R, src, dst, P);

  // 5. h2 = relu(agg2@rel2 + b + h1@root2) -> Q  [N,128]  (RPB=32)
  k_gemm<HIDDEN, 2 * HIDDEN, true, true><<<(N_NODES + 31) / 32, 256, 0, stream>>>(
      P, R, rel2w, root2w, rel2b, Q);

  // 6. agg3 = scatter(h2) -> R  [N,128]
  hipMemsetAsync(R, 0, (size_t)N_NODES * 128 * sizeof(float), stream);
  k_scatter<128><<<(N_EDGES * 128u + 255u) / 256u, 256, 0, stream>>>(Q, src, dst, R);

  // 7. h3 = relu(agg3@rel3 + b + h2@root3) -> P  [N,128]  (RPB=32)
  k_gemm<2 * HIDDEN, OUT_CH, true, true><<<(N_NODES + 31) / 32, 256, 0, stream>>>(
      R, Q, rel3w, root3w, rel3b, P);

  // 8. global mean pool
  hipMemsetAsync(S, 0, ((size_t)NUM_G * OUT_CH + NUM_G) * sizeof(float), stream);
  k_pool<<<(N_NODES * 128 + 255) / 256, 256, 0, stream>>>(P, batch, S);
  k_count<<<(N_NODES + 255) / 256, 256, 0, stream>>>(batch, C);

  // 9. head
  k_head<<<(NUM_G * NUM_CLS + 255) / 256, 256, 0, stream>>>(S, C, linw, linb, out);
}

// Round 3
// 515.941 us; speedup vs baseline: 3.0662x; 1.9727x over previous
//
#include <hip/hip_runtime.h>

#define N_NODES 50000
#define N_EDGES 800000
#define IN_DIM  128
#define IN_CH   64
#define HIDDEN  64
#define OUT_CH  128
#define NUM_CLS 16
#define NUM_G   512
#define SCAN_NB ((N_NODES + 255) / 256)   // 196

// ============ register-tiled GEMM: out = [relu](A@Wa [+ H@Wh] + bias) ============
template <int DIN, int DOUT, bool HAS_ROOT, bool RELU>
__global__ __launch_bounds__(256) void k_gemm(
    const float* __restrict__ A, const float* __restrict__ H,
    const float* __restrict__ Wa, const float* __restrict__ Wh,
    const float* __restrict__ bias, float* __restrict__ out) {
  constexpr int TM = 4, TN = 4;
  constexpr int CG = DOUT / TN;
  constexpr int RG = 256 / CG;
  constexpr int RPB = RG * TM;
  constexpr int LDA = DIN + 4;

  __shared__ float sA[RPB * LDA];
  __shared__ float sH[HAS_ROOT ? RPB * LDA : 4];

  const int tid = threadIdx.x;
  const int row0 = blockIdx.x * RPB;

  constexpr int NF4 = RPB * DIN / 4;
#pragma unroll
  for (int i = tid; i < NF4; i += 256) {
    int flat = i * 4;
    int r = flat / DIN;
    int k = flat - r * DIN;
    int grow = row0 + r;
    float4 va = make_float4(0.f, 0.f, 0.f, 0.f);
    float4 vh = make_float4(0.f, 0.f, 0.f, 0.f);
    if (grow < N_NODES) {
      va = *(const float4*)&A[(size_t)grow * DIN + k];
      if constexpr (HAS_ROOT) vh = *(const float4*)&H[(size_t)grow * DIN + k];
    }
    *(float4*)&sA[r * LDA + k] = va;
    if constexpr (HAS_ROOT) *(float4*)&sH[r * LDA + k] = vh;
  }
  __syncthreads();

  const int cg = tid % CG;
  const int rg = tid / CG;
  const int col0 = cg * TN;
  const int rbase = rg * TM;

  float acc[TM][TN];
#pragma unroll
  for (int i = 0; i < TM; ++i)
#pragma unroll
    for (int j = 0; j < TN; ++j) acc[i][j] = 0.f;

#pragma unroll 4
  for (int k = 0; k < DIN; ++k) {
    float4 wa = *(const float4*)&Wa[k * DOUT + col0];
    float4 wh;
    if constexpr (HAS_ROOT) wh = *(const float4*)&Wh[k * DOUT + col0];
#pragma unroll
    for (int i = 0; i < TM; ++i) {
      float a = sA[(rbase + i) * LDA + k];
      acc[i][0] = fmaf(a, wa.x, acc[i][0]);
      acc[i][1] = fmaf(a, wa.y, acc[i][1]);
      acc[i][2] = fmaf(a, wa.z, acc[i][2]);
      acc[i][3] = fmaf(a, wa.w, acc[i][3]);
      if constexpr (HAS_ROOT) {
        float hh = sH[(rbase + i) * LDA + k];
        acc[i][0] = fmaf(hh, wh.x, acc[i][0]);
        acc[i][1] = fmaf(hh, wh.y, acc[i][1]);
        acc[i][2] = fmaf(hh, wh.z, acc[i][2]);
        acc[i][3] = fmaf(hh, wh.w, acc[i][3]);
      }
    }
  }

  float4 bv = *(const float4*)&bias[col0];
#pragma unroll
  for (int i = 0; i < TM; ++i) {
    int grow = row0 + rbase + i;
    if (grow < N_NODES) {
      float4 o;
      o.x = acc[i][0] + bv.x;
      o.y = acc[i][1] + bv.y;
      o.z = acc[i][2] + bv.z;
      o.w = acc[i][3] + bv.w;
      if constexpr (RELU) {
        o.x = fmaxf(o.x, 0.f); o.y = fmaxf(o.y, 0.f);
        o.z = fmaxf(o.z, 0.f); o.w = fmaxf(o.w, 0.f);
      }
      *(float4*)&out[(size_t)grow * DOUT + col0] = o;
    }
  }
}

// ================= CSR build (per call; edge_index is input) =================
__global__ __launch_bounds__(256) void k_hist(const int* __restrict__ dst,
                                              int* __restrict__ deg) {
  int e = blockIdx.x * 256 + threadIdx.x;
  if (e < N_EDGES) atomicAdd(&deg[dst[e]], 1);
}

__global__ __launch_bounds__(256) void k_scan_partial(const int* __restrict__ deg,
                                                      int* __restrict__ partial) {
  __shared__ int s[256];
  int i = blockIdx.x * 256 + threadIdx.x;
  s[threadIdx.x] = (i < N_NODES) ? deg[i] : 0;
  __syncthreads();
  for (int st = 128; st > 0; st >>= 1) {
    if (threadIdx.x < st) s[threadIdx.x] += s[threadIdx.x + st];
    __syncthreads();
  }
  if (threadIdx.x == 0) partial[blockIdx.x] = s[0];
}

// in-place exclusive scan of SCAN_NB (<=256) partials, single block
__global__ __launch_bounds__(256) void k_scan_top(int* __restrict__ partial) {
  __shared__ int s[256];
  int t = threadIdx.x;
  int v0 = (t < SCAN_NB) ? partial[t] : 0;
  s[t] = v0;
  __syncthreads();
  for (int st = 1; st < 256; st <<= 1) {
    int v = (t >= st) ? s[t - st] : 0;
    __syncthreads();
    s[t] += v;
    __syncthreads();
  }
  if (t < SCAN_NB) partial[t] = s[t] - v0;   // exclusive
}

__global__ __launch_bounds__(256) void k_scan_final(const int* __restrict__ deg,
    const int* __restrict__ partial, int* __restrict__ off) {
  __shared__ int s[256];
  int i = blockIdx.x * 256 + threadIdx.x;
  int v0 = (i < N_NODES) ? deg[i] : 0;
  s[threadIdx.x] = v0;
  __syncthreads();
  for (int st = 1; st < 256; st <<= 1) {
    int v = (threadIdx.x >= st) ? s[threadIdx.x - st] : 0;
    __syncthreads();
    s[threadIdx.x] += v;
    __syncthreads();
  }
  if (i < N_NODES) off[i] = partial[blockIdx.x] + s[threadIdx.x] - v0;
  if (i == 0) off[N_NODES] = N_EDGES;
}

__global__ __launch_bounds__(256) void k_reorder(const int* __restrict__ src,
    const int* __restrict__ dst, const int* __restrict__ off,
    int* __restrict__ cur, int* __restrict__ esrc) {
  int e = blockIdx.x * 256 + threadIdx.x;
  if (e >= N_EDGES) return;
  int d = dst[e];
  int pos = off[d] + atomicAdd(&cur[d], 1);
  esrc[pos] = src[e];
}

// ============ deterministic gather: agg[n] = sum_{e in CSR[n]} h[esrc[e]] ============
template <int D>
__global__ __launch_bounds__(256) void k_gather(const float* __restrict__ h,
    const int* __restrict__ esrc, const int* __restrict__ off,
    float* __restrict__ agg) {
  int w = (blockIdx.x * 256 + threadIdx.x) >> 6;   // one wave per node
  int lane = threadIdx.x & 63;
  if (w >= N_NODES) return;
  int beg = off[w], end = off[w + 1];
  if constexpr (D == 64) {
    float acc = 0.f;
    int e = beg;
    for (; e + 4 <= end; e += 4) {
      int s0 = esrc[e], s1 = esrc[e + 1], s2 = esrc[e + 2], s3 = esrc[e + 3];
      float a0 = h[(size_t)s0 * 64 + lane];
      float a1 = h[(size_t)s1 * 64 + lane];
      float a2 = h[(size_t)s2 * 64 + lane];
      float a3 = h[(size_t)s3 * 64 + lane];
      acc += (a0 + a1) + (a2 + a3);
    }
    for (; e < end; ++e) acc += h[(size_t)esrc[e] * 64 + lane];
    agg[(size_t)w * 64 + lane] = acc;
  } else {
    float accx = 0.f, accy = 0.f;
    int e = beg;
    for (; e + 2 <= end; e += 2) {
      int s0 = esrc[e], s1 = esrc[e + 1];
      float2 a = *(const float2*)&h[(size_t)s0 * 128 + 2 * lane];
      float2 b = *(const float2*)&h[(size_t)s1 * 128 + 2 * lane];
      accx += a.x + b.x;
      accy += a.y + b.y;
    }
    if (e < end) {
      float2 a = *(const float2*)&h[(size_t)esrc[e] * 128 + 2 * lane];
      accx += a.x;
      accy += a.y;
    }
    float2 o = make_float2(accx, accy);
    *(float2*)&agg[(size_t)w * 128 + 2 * lane] = o;
  }
}

// ================= pooling via sorted batch segments =================
__device__ inline int lbound(const int* __restrict__ a, int n, int v) {
  int lo = 0, hi = n;
  while (lo < hi) {
    int m = (lo + hi) >> 1;
    if (a[m] < v) lo = m + 1; else hi = m;
  }
  return lo;
}

__global__ __launch_bounds__(128) void k_pool(const float* __restrict__ h3,
    const int* __restrict__ batch, float* __restrict__ pooled) {
  int g = blockIdx.x;
  int lo = lbound(batch, N_NODES, g);
  int hi = lbound(batch, N_NODES, g + 1);
  float acc = 0.f;
  for (int r = lo; r < hi; ++r) acc += h3[(size_t)r * OUT_CH + threadIdx.x];
  float inv = (hi > lo) ? 1.f / (float)(hi - lo) : 0.f;
  pooled[(size_t)g * OUT_CH + threadIdx.x] = acc * inv;
}

// ================= head: out = pooled @ lin_w + lin_b =================
__global__ __launch_bounds__(256) void k_head(const float* __restrict__ pooled,
    const float* __restrict__ lw, const float* __restrict__ lb,
    float* __restrict__ out) {
  int t = blockIdx.x * 256 + threadIdx.x;
  if (t >= NUM_G * NUM_CLS) return;
  int g = t >> 4;
  int c = t & 15;
  float s = lb[c];
#pragma unroll
  for (int k = 0; k < OUT_CH; ++k)
    s = fmaf(pooled[(size_t)g * OUT_CH + k], lw[k * NUM_CLS + c], s);
  out[t] = s;
}

extern "C" void kernel_launch(void* const* d_in, const int* in_sizes, int n_in,
                              void* d_out, int out_size, void* d_ws, size_t ws_size,
                              hipStream_t stream) {
  const float* x      = (const float*)d_in[0];
  const int*   ei     = (const int*)d_in[1];
  const int*   batch  = (const int*)d_in[2];
  const float* w1     = (const float*)d_in[4];
  const float* b1     = (const float*)d_in[5];
  const float* rel1w  = (const float*)d_in[6];
  const float* rel1b  = (const float*)d_in[7];
  const float* root1w = (const float*)d_in[8];
  const float* rel2w  = (const float*)d_in[9];
  const float* rel2b  = (const float*)d_in[10];
  const float* root2w = (const float*)d_in[11];
  const float* rel3w  = (const float*)d_in[12];
  const float* rel3b  = (const float*)d_in[13];
  const float* root3w = (const float*)d_in[14];
  const float* linw   = (const float*)d_in[15];
  const float* linb   = (const float*)d_in[16];
  const int* src = ei;
  const int* dst = ei + N_EDGES;
  float* out = (float*)d_out;

  // ---- workspace layout ----
  float* P = (float*)d_ws;                             // [N,128]
  float* Q = P + (size_t)N_NODES * 128;                // [N,128]
  float* R = Q + (size_t)N_NODES * 128;                // [N,128]
  float* pooled = R + (size_t)N_NODES * 128;           // [G,128]
  int* deg     = (int*)(pooled + (size_t)NUM_G * OUT_CH);
  int* off     = deg + N_NODES;                        // N+1
  int* cur     = off + (N_NODES + 1);
  int* partial = cur + N_NODES;                        // 256
  int* esrc    = partial + 256;                        // [E]

  // ---- CSR build ----
  hipMemsetAsync(deg, 0, (size_t)N_NODES * sizeof(int), stream);
  hipMemsetAsync(cur, 0, (size_t)N_NODES * sizeof(int), stream);
  k_hist<<<(N_EDGES + 255) / 256, 256, 0, stream>>>(dst, deg);
  k_scan_partial<<<SCAN_NB, 256, 0, stream>>>(deg, partial);
  k_scan_top<<<1, 256, 0, stream>>>(partial);
  k_scan_final<<<SCAN_NB, 256, 0, stream>>>(deg, partial, off);
  k_reorder<<<(N_EDGES + 255) / 256, 256, 0, stream>>>(src, dst, off, cur, esrc);

  // ---- stage1: h0 = x@w1 + b1 -> P ----
  k_gemm<IN_DIM, IN_CH, false, false><<<(N_NODES + 63) / 64, 256, 0, stream>>>(
      x, nullptr, w1, nullptr, b1, P);

  // ---- layer1 ----
  k_gather<64><<<(N_NODES * 64 + 255) / 256, 256, 0, stream>>>(P, esrc, off, Q);
  k_gemm<IN_CH, HIDDEN, true, true><<<(N_NODES + 63) / 64, 256, 0, stream>>>(
      Q, P, rel1w, root1w, rel1b, R);

  // ---- layer2 ----
  k_gather<64><<<(N_NODES * 64 + 255) / 256, 256, 0, stream>>>(R, esrc, off, P);
  k_gemm<HIDDEN, 2 * HIDDEN, true, true><<<(N_NODES + 31) / 32, 256, 0, stream>>>(
      P, R, rel2w, root2w, rel2b, Q);

  // ---- layer3 ----
  k_gather<128><<<(N_NODES * 64 + 255) / 256, 256, 0, stream>>>(Q, esrc, off, R);
  k_gemm<2 * HIDDEN, OUT_CH, true, true><<<(N_NODES + 31) / 32, 256, 0, stream>>>(
      R, Q, rel3w, root3w, rel3b, P);

  // ---- pool (sorted batch -> segment mean) + head ----
  k_pool<<<NUM_G, 128, 0, stream>>>(P, batch, pooled);
  k_head<<<(NUM_G * NUM_CLS + 255) / 256, 256, 0, stream>>>(pooled, linw, linb, out);
}

// Round 4
// 399.483 us; speedup vs baseline: 3.9601x; 1.2915x over previous
//
#include <hip/hip_runtime.h>
#include <hip/hip_bf16.h>

#define N_NODES 50000
#define N_EDGES 800000
#define IN_DIM  128
#define IN_CH   64
#define HIDDEN  64
#define OUT_CH  128
#define NUM_CLS 16
#define NUM_G   512
#define SCAN_NB ((N_NODES + 255) / 256)   // 196

typedef __attribute__((ext_vector_type(8))) short short8;
typedef __attribute__((ext_vector_type(4))) float f32x4;

__device__ inline float bits2f(unsigned short u) {
  unsigned x = (unsigned)u << 16;
  float f;
  __builtin_memcpy(&f, &x, 4);
  return f;
}
__device__ inline unsigned short f2bits(float v) {
  __hip_bfloat16 b = __float2bfloat16(v);   // RNE
  unsigned short s;
  __builtin_memcpy(&s, &b, 2);
  return s;
}
__device__ inline short8 zero8() {
  short8 z;
#pragma unroll
  for (int i = 0; i < 8; ++i) z[i] = 0;
  return z;
}

// ============ MFMA GEMM: out(bf16) = [relu](A@Wa [+ H@Wh] + bias) ============
// 256 thr = 4 waves; each wave: 2 row-tiles of 16 -> 32 rows; block = 128 rows.
// Wa/Wh pre-packed in B-fragment order: [((kt*CT+ct)*64+lane)*8+j].
// A-frag: lane holds A[row0+ (lane&15)][kt*32 + (lane>>4)*8 + j].
// C/D: col = lane&15, row = (lane>>4)*4 + reg   [verified layout]
template <int DIN, int DOUT, bool ROOT, bool RELU, bool AFP32>
__global__ __launch_bounds__(256) void k_mfma(
    const void* __restrict__ Ap, const unsigned short* __restrict__ Hp,
    const short* __restrict__ Wa, const short* __restrict__ Wh,
    const float* __restrict__ bias, unsigned short* __restrict__ outp) {
  constexpr int KT = DIN / 32;
  constexpr int CT = DOUT / 16;
  const int wave = threadIdx.x >> 6;
  const int lane = threadIdx.x & 63;
  const int m = lane & 15;
  const int q = lane >> 4;
  const int rbase = blockIdx.x * 128 + wave * 32;

  short8 afr[2][KT];
  short8 hfr[2][KT];   // unused (DCE'd) when !ROOT

#pragma unroll
  for (int rt = 0; rt < 2; ++rt) {
    int row = rbase + rt * 16 + m;
    bool ok = row < N_NODES;
#pragma unroll
    for (int kt = 0; kt < KT; ++kt) {
      if constexpr (AFP32) {
        short8 f = zero8();
        if (ok) {
          const float* ap = (const float*)Ap + (size_t)row * DIN + kt * 32 + q * 8;
          float4 x0 = *(const float4*)ap;
          float4 x1 = *(const float4*)(ap + 4);
          f[0] = (short)f2bits(x0.x); f[1] = (short)f2bits(x0.y);
          f[2] = (short)f2bits(x0.z); f[3] = (short)f2bits(x0.w);
          f[4] = (short)f2bits(x1.x); f[5] = (short)f2bits(x1.y);
          f[6] = (short)f2bits(x1.z); f[7] = (short)f2bits(x1.w);
        }
        afr[rt][kt] = f;
      } else {
        afr[rt][kt] = ok ? *(const short8*)((const unsigned short*)Ap +
                              (size_t)row * DIN + kt * 32 + q * 8)
                         : zero8();
      }
      if constexpr (ROOT) {
        hfr[rt][kt] = ok ? *(const short8*)(Hp + (size_t)row * DIN + kt * 32 + q * 8)
                         : zero8();
      }
    }
  }

  for (int ct = 0; ct < CT; ++ct) {
    f32x4 acc0 = {0.f, 0.f, 0.f, 0.f};
    f32x4 acc1 = {0.f, 0.f, 0.f, 0.f};
#pragma unroll
    for (int kt = 0; kt < KT; ++kt) {
      short8 b = *(const short8*)(Wa + ((size_t)(kt * CT + ct) * 64 + lane) * 8);
      acc0 = __builtin_amdgcn_mfma_f32_16x16x32_bf16(afr[0][kt], b, acc0, 0, 0, 0);
      acc1 = __builtin_amdgcn_mfma_f32_16x16x32_bf16(afr[1][kt], b, acc1, 0, 0, 0);
      if constexpr (ROOT) {
        short8 bh = *(const short8*)(Wh + ((size_t)(kt * CT + ct) * 64 + lane) * 8);
        acc0 = __builtin_amdgcn_mfma_f32_16x16x32_bf16(hfr[0][kt], bh, acc0, 0, 0, 0);
        acc1 = __builtin_amdgcn_mfma_f32_16x16x32_bf16(hfr[1][kt], bh, acc1, 0, 0, 0);
      }
    }
    float bv = bias[ct * 16 + m];
#pragma unroll
    for (int r = 0; r < 4; ++r) {
      int row0 = rbase + q * 4 + r;
      int row1 = row0 + 16;
      float v0 = acc0[r] + bv;
      float v1 = acc1[r] + bv;
      if constexpr (RELU) { v0 = fmaxf(v0, 0.f); v1 = fmaxf(v1, 0.f); }
      if (row0 < N_NODES) outp[(size_t)row0 * DOUT + ct * 16 + m] = f2bits(v0);
      if (row1 < N_NODES) outp[(size_t)row1 * DOUT + ct * 16 + m] = f2bits(v1);
    }
  }
}

// ============ weight pack: fp32 [DIN x DOUT] -> bf16 B-fragment layout ============
template <int DIN, int DOUT>
__global__ __launch_bounds__(256) void k_packw(const float* __restrict__ W,
                                               short* __restrict__ o) {
  int t = blockIdx.x * 256 + threadIdx.x;
  if (t >= DIN * DOUT) return;
  constexpr int CT = DOUT / 16;
  int j = t & 7;
  int lane = (t >> 3) & 63;
  int kc = t >> 9;               // kt*CT + ct
  int ct = kc % CT;
  int kt = kc / CT;
  int k = kt * 32 + (lane >> 4) * 8 + j;
  int n = ct * 16 + (lane & 15);
  o[t] = (short)f2bits(W[k * DOUT + n]);
}

// ================= CSR build =================
__global__ __launch_bounds__(256) void k_hist(const int* __restrict__ dst,
                                              int* __restrict__ deg) {
  int e = blockIdx.x * 256 + threadIdx.x;
  if (e < N_EDGES) atomicAdd(&deg[dst[e]], 1);
}

__global__ __launch_bounds__(256) void k_scan_partial(const int* __restrict__ deg,
                                                      int* __restrict__ partial) {
  __shared__ int s[256];
  int i = blockIdx.x * 256 + threadIdx.x;
  s[threadIdx.x] = (i < N_NODES) ? deg[i] : 0;
  __syncthreads();
  for (int st = 128; st > 0; st >>= 1) {
    if (threadIdx.x < st) s[threadIdx.x] += s[threadIdx.x + st];
    __syncthreads();
  }
  if (threadIdx.x == 0) partial[blockIdx.x] = s[0];
}

__global__ __launch_bounds__(256) void k_scan_top(int* __restrict__ partial) {
  __shared__ int s[256];
  int t = threadIdx.x;
  int v0 = (t < SCAN_NB) ? partial[t] : 0;
  s[t] = v0;
  __syncthreads();
  for (int st = 1; st < 256; st <<= 1) {
    int v = (t >= st) ? s[t - st] : 0;
    __syncthreads();
    s[t] += v;
    __syncthreads();
  }
  if (t < SCAN_NB) partial[t] = s[t] - v0;
}

__global__ __launch_bounds__(256) void k_scan_final(const int* __restrict__ deg,
    const int* __restrict__ partial, int* __restrict__ off) {
  __shared__ int s[256];
  int i = blockIdx.x * 256 + threadIdx.x;
  int v0 = (i < N_NODES) ? deg[i] : 0;
  s[threadIdx.x] = v0;
  __syncthreads();
  for (int st = 1; st < 256; st <<= 1) {
    int v = (threadIdx.x >= st) ? s[threadIdx.x - st] : 0;
    __syncthreads();
    s[threadIdx.x] += v;
    __syncthreads();
  }
  if (i < N_NODES) off[i] = partial[blockIdx.x] + s[threadIdx.x] - v0;
  if (i == 0) off[N_NODES] = N_EDGES;
}

__global__ __launch_bounds__(256) void k_reorder(const int* __restrict__ src,
    const int* __restrict__ dst, const int* __restrict__ off,
    int* __restrict__ cur, int* __restrict__ esrc) {
  int e = blockIdx.x * 256 + threadIdx.x;
  if (e >= N_EDGES) return;
  int d = dst[e];
  int pos = off[d] + atomicAdd(&cur[d], 1);
  esrc[pos] = src[e];
}

// ============ gathers (bf16 in, fp32 accumulate, bf16 out) ============
// D=64: 128-B rows; 2 nodes per wave, lane -> feature pair (lane&31)
__global__ __launch_bounds__(256) void k_gather64(const unsigned short* __restrict__ h,
    const int* __restrict__ esrc, const int* __restrict__ off,
    unsigned short* __restrict__ agg) {
  int gw = (blockIdx.x * 256 + threadIdx.x) >> 6;
  int lane = threadIdx.x & 63;
  int node = gw * 2 + (lane >> 5);
  int fp = lane & 31;
  if (node >= N_NODES) return;
  int e = off[node], end = off[node + 1];
  float ax = 0.f, ay = 0.f;
  for (; e + 2 <= end; e += 2) {
    int s0 = esrc[e], s1 = esrc[e + 1];
    unsigned v0 = *(const unsigned*)(h + (size_t)s0 * 64 + fp * 2);
    unsigned v1 = *(const unsigned*)(h + (size_t)s1 * 64 + fp * 2);
    ax += bits2f((unsigned short)v0) + bits2f((unsigned short)v1);
    ay += bits2f((unsigned short)(v0 >> 16)) + bits2f((unsigned short)(v1 >> 16));
  }
  if (e < end) {
    unsigned v0 = *(const unsigned*)(h + (size_t)esrc[e] * 64 + fp * 2);
    ax += bits2f((unsigned short)v0);
    ay += bits2f((unsigned short)(v0 >> 16));
  }
  unsigned o = (unsigned)f2bits(ax) | ((unsigned)f2bits(ay) << 16);
  *(unsigned*)(agg + (size_t)node * 64 + fp * 2) = o;
}

// D=128: 256-B rows; 1 node per wave, lane -> feature pair
__global__ __launch_bounds__(256) void k_gather128(const unsigned short* __restrict__ h,
    const int* __restrict__ esrc, const int* __restrict__ off,
    unsigned short* __restrict__ agg) {
  int node = (blockIdx.x * 256 + threadIdx.x) >> 6;
  int fp = threadIdx.x & 63;
  if (node >= N_NODES) return;
  int e = off[node], end = off[node + 1];
  float ax = 0.f, ay = 0.f;
  for (; e + 2 <= end; e += 2) {
    int s0 = esrc[e], s1 = esrc[e + 1];
    unsigned v0 = *(const unsigned*)(h + (size_t)s0 * 128 + fp * 2);
    unsigned v1 = *(const unsigned*)(h + (size_t)s1 * 128 + fp * 2);
    ax += bits2f((unsigned short)v0) + bits2f((unsigned short)v1);
    ay += bits2f((unsigned short)(v0 >> 16)) + bits2f((unsigned short)(v1 >> 16));
  }
  if (e < end) {
    unsigned v0 = *(const unsigned*)(h + (size_t)esrc[e] * 128 + fp * 2);
    ax += bits2f((unsigned short)v0);
    ay += bits2f((unsigned short)(v0 >> 16));
  }
  unsigned o = (unsigned)f2bits(ax) | ((unsigned)f2bits(ay) << 16);
  *(unsigned*)(agg + (size_t)node * 128 + fp * 2) = o;
}

// ================= pooling (sorted batch) =================
__device__ inline int lbound(const int* __restrict__ a, int n, int v) {
  int lo = 0, hi = n;
  while (lo < hi) {
    int m = (lo + hi) >> 1;
    if (a[m] < v) lo = m + 1; else hi = m;
  }
  return lo;
}

__global__ __launch_bounds__(128) void k_pool(const unsigned short* __restrict__ h3,
    const int* __restrict__ batch, float* __restrict__ pooled) {
  int g = blockIdx.x;
  int lo = lbound(batch, N_NODES, g);
  int hi = lbound(batch, N_NODES, g + 1);
  float acc = 0.f;
  for (int r = lo; r < hi; ++r) acc += bits2f(h3[(size_t)r * OUT_CH + threadIdx.x]);
  float inv = (hi > lo) ? 1.f / (float)(hi - lo) : 0.f;
  pooled[(size_t)g * OUT_CH + threadIdx.x] = acc * inv;
}

// ================= head (fp32) =================
__global__ __launch_bounds__(256) void k_head(const float* __restrict__ pooled,
    const float* __restrict__ lw, const float* __restrict__ lb,
    float* __restrict__ out) {
  int t = blockIdx.x * 256 + threadIdx.x;
  if (t >= NUM_G * NUM_CLS) return;
  int g = t >> 4;
  int c = t & 15;
  float s = lb[c];
#pragma unroll
  for (int k = 0; k < OUT_CH; ++k)
    s = fmaf(pooled[(size_t)g * OUT_CH + k], lw[k * NUM_CLS + c], s);
  out[t] = s;
}

extern "C" void kernel_launch(void* const* d_in, const int* in_sizes, int n_in,
                              void* d_out, int out_size, void* d_ws, size_t ws_size,
                              hipStream_t stream) {
  const float* x      = (const float*)d_in[0];
  const int*   ei     = (const int*)d_in[1];
  const int*   batch  = (const int*)d_in[2];
  const float* w1     = (const float*)d_in[4];
  const float* b1     = (const float*)d_in[5];
  const float* rel1w  = (const float*)d_in[6];
  const float* rel1b  = (const float*)d_in[7];
  const float* root1w = (const float*)d_in[8];
  const float* rel2w  = (const float*)d_in[9];
  const float* rel2b  = (const float*)d_in[10];
  const float* root2w = (const float*)d_in[11];
  const float* rel3w  = (const float*)d_in[12];
  const float* rel3b  = (const float*)d_in[13];
  const float* root3w = (const float*)d_in[14];
  const float* linw   = (const float*)d_in[15];
  const float* linb   = (const float*)d_in[16];
  const int* src = ei;
  const int* dst = ei + N_EDGES;
  float* out = (float*)d_out;

  // ---- workspace layout (bf16 first, 16B-aligned blocks) ----
  unsigned short* P = (unsigned short*)d_ws;            // [N,128] bf16
  unsigned short* Q = P + (size_t)N_NODES * 128;        // [N,128] bf16
  unsigned short* R = Q + (size_t)N_NODES * 128;        // [N,128] bf16
  short* WP = (short*)(R + (size_t)N_NODES * 128);      // 65536 packed bf16 weights
  short* w1p  = WP;                 // 128x64  -> 8192
  short* r1p  = w1p + 8192;         // 64x64   -> 4096
  short* o1p  = r1p + 4096;         // 64x64   -> 4096
  short* r2p  = o1p + 4096;         // 64x128  -> 8192
  short* o2p  = r2p + 8192;         // 64x128  -> 8192
  short* r3p  = o2p + 8192;         // 128x128 -> 16384
  short* o3p  = r3p + 16384;        // 128x128 -> 16384
  float* pooled = (float*)(o3p + 16384);                // [G,128] fp32
  int* deg     = (int*)(pooled + (size_t)NUM_G * OUT_CH);
  int* off     = deg + N_NODES;                         // N+1
  int* cur     = off + (N_NODES + 1);
  int* partial = cur + N_NODES;                         // 256
  int* esrc    = partial + 256;                         // [E]

  // ---- CSR build ----
  hipMemsetAsync(deg, 0, (size_t)N_NODES * sizeof(int), stream);
  hipMemsetAsync(cur, 0, (size_t)N_NODES * sizeof(int), stream);
  k_hist<<<(N_EDGES + 255) / 256, 256, 0, stream>>>(dst, deg);
  k_scan_partial<<<SCAN_NB, 256, 0, stream>>>(deg, partial);
  k_scan_top<<<1, 256, 0, stream>>>(partial);
  k_scan_final<<<SCAN_NB, 256, 0, stream>>>(deg, partial, off);
  k_reorder<<<(N_EDGES + 255) / 256, 256, 0, stream>>>(src, dst, off, cur, esrc);

  // ---- pack weights to bf16 fragment layout ----
  k_packw<128, 64><<<32, 256, 0, stream>>>(w1, w1p);
  k_packw<64, 64><<<16, 256, 0, stream>>>(rel1w, r1p);
  k_packw<64, 64><<<16, 256, 0, stream>>>(root1w, o1p);
  k_packw<64, 128><<<32, 256, 0, stream>>>(rel2w, r2p);
  k_packw<64, 128><<<32, 256, 0, stream>>>(root2w, o2p);
  k_packw<128, 128><<<64, 256, 0, stream>>>(rel3w, r3p);
  k_packw<128, 128><<<64, 256, 0, stream>>>(root3w, o3p);

  const int GB = (N_NODES + 127) / 128;   // 391 blocks for MFMA GEMMs

  // ---- stage1: h0 = x@w1 + b1 -> P (bf16) ----
  k_mfma<128, 64, false, false, true><<<GB, 256, 0, stream>>>(
      x, nullptr, w1p, nullptr, b1, P);

  // ---- layer1 ----
  k_gather64<<<(N_NODES + 7) / 8, 256, 0, stream>>>(P, esrc, off, Q);
  k_mfma<64, 64, true, true, false><<<GB, 256, 0, stream>>>(
      Q, P, r1p, o1p, rel1b, R);

  // ---- layer2 ----
  k_gather64<<<(N_NODES + 7) / 8, 256, 0, stream>>>(R, esrc, off, P);
  k_mfma<64, 128, true, true, false><<<GB, 256, 0, stream>>>(
      P, R, r2p, o2p, rel2b, Q);

  // ---- layer3 ----
  k_gather128<<<(N_NODES + 3) / 4, 256, 0, stream>>>(Q, esrc, off, R);
  k_mfma<128, 128, true, true, false><<<GB, 256, 0, stream>>>(
      R, Q, r3p, o3p, rel3b, P);

  // ---- pool + head ----
  k_pool<<<NUM_G, 128, 0, stream>>>(P, batch, pooled);
  k_head<<<(NUM_G * NUM_CLS + 255) / 256, 256, 0, stream>>>(pooled, linw, linb, out);
}

// Round 5
// 336.698 us; speedup vs baseline: 4.6986x; 1.1865x over previous
//
#include <hip/hip_runtime.h>
#include <hip/hip_bf16.h>

#define N_NODES 50000
#define N_EDGES 800000
#define IN_DIM  128
#define IN_CH   64
#define HIDDEN  64
#define OUT_CH  128
#define NUM_CLS 16
#define NUM_G   512
#define SCAN_NB ((N_NODES + 255) / 256)   // 196

typedef __attribute__((ext_vector_type(8))) short short8;
typedef __attribute__((ext_vector_type(4))) float f32x4;

__device__ inline float bits2f(unsigned short u) {
  unsigned x = (unsigned)u << 16;
  float f;
  __builtin_memcpy(&f, &x, 4);
  return f;
}
__device__ inline unsigned short f2bits(float v) {
  __hip_bfloat16 b = __float2bfloat16(v);   // RNE
  unsigned short s;
  __builtin_memcpy(&s, &b, 2);
  return s;
}
__device__ inline short8 zero8() {
  short8 z;
#pragma unroll
  for (int i = 0; i < 8; ++i) z[i] = 0;
  return z;
}
__device__ inline void acc2(float& a0, float& a1, unsigned v) {
  a0 += bits2f((unsigned short)v);
  a1 += bits2f((unsigned short)(v >> 16));
}

// ============ MFMA GEMM: out(bf16) = [relu](A@Wa [+ H@Wh] + bias) ============
// 256 thr = 4 waves; each wave: 2 row-tiles of 16 -> 32 rows; block = 128 rows.
// Wa/Wh pre-packed in B-fragment order: [((kt*CT+ct)*64+lane)*8+j].
// C/D: col = lane&15, row = (lane>>4)*4 + reg
template <int DIN, int DOUT, bool ROOT, bool RELU, bool AFP32>
__global__ __launch_bounds__(256) void k_mfma(
    const void* __restrict__ Ap, const unsigned short* __restrict__ Hp,
    const short* __restrict__ Wa, const short* __restrict__ Wh,
    const float* __restrict__ bias, unsigned short* __restrict__ outp) {
  constexpr int KT = DIN / 32;
  constexpr int CT = DOUT / 16;
  const int wave = threadIdx.x >> 6;
  const int lane = threadIdx.x & 63;
  const int m = lane & 15;
  const int q = lane >> 4;
  const int rbase = blockIdx.x * 128 + wave * 32;

  short8 afr[2][KT];
  short8 hfr[2][KT];

#pragma unroll
  for (int rt = 0; rt < 2; ++rt) {
    int row = rbase + rt * 16 + m;
    bool ok = row < N_NODES;
#pragma unroll
    for (int kt = 0; kt < KT; ++kt) {
      if constexpr (AFP32) {
        short8 f = zero8();
        if (ok) {
          const float* ap = (const float*)Ap + (size_t)row * DIN + kt * 32 + q * 8;
          float4 x0 = *(const float4*)ap;
          float4 x1 = *(const float4*)(ap + 4);
          f[0] = (short)f2bits(x0.x); f[1] = (short)f2bits(x0.y);
          f[2] = (short)f2bits(x0.z); f[3] = (short)f2bits(x0.w);
          f[4] = (short)f2bits(x1.x); f[5] = (short)f2bits(x1.y);
          f[6] = (short)f2bits(x1.z); f[7] = (short)f2bits(x1.w);
        }
        afr[rt][kt] = f;
      } else {
        afr[rt][kt] = ok ? *(const short8*)((const unsigned short*)Ap +
                              (size_t)row * DIN + kt * 32 + q * 8)
                         : zero8();
      }
      if constexpr (ROOT) {
        hfr[rt][kt] = ok ? *(const short8*)(Hp + (size_t)row * DIN + kt * 32 + q * 8)
                         : zero8();
      }
    }
  }

  for (int ct = 0; ct < CT; ++ct) {
    f32x4 acc0 = {0.f, 0.f, 0.f, 0.f};
    f32x4 acc1 = {0.f, 0.f, 0.f, 0.f};
#pragma unroll
    for (int kt = 0; kt < KT; ++kt) {
      short8 b = *(const short8*)(Wa + ((size_t)(kt * CT + ct) * 64 + lane) * 8);
      acc0 = __builtin_amdgcn_mfma_f32_16x16x32_bf16(afr[0][kt], b, acc0, 0, 0, 0);
      acc1 = __builtin_amdgcn_mfma_f32_16x16x32_bf16(afr[1][kt], b, acc1, 0, 0, 0);
      if constexpr (ROOT) {
        short8 bh = *(const short8*)(Wh + ((size_t)(kt * CT + ct) * 64 + lane) * 8);
        acc0 = __builtin_amdgcn_mfma_f32_16x16x32_bf16(hfr[0][kt], bh, acc0, 0, 0, 0);
        acc1 = __builtin_amdgcn_mfma_f32_16x16x32_bf16(hfr[1][kt], bh, acc1, 0, 0, 0);
      }
    }
    float bv = bias[ct * 16 + m];
#pragma unroll
    for (int r = 0; r < 4; ++r) {
      int row0 = rbase + q * 4 + r;
      int row1 = row0 + 16;
      float v0 = acc0[r] + bv;
      float v1 = acc1[r] + bv;
      if constexpr (RELU) { v0 = fmaxf(v0, 0.f); v1 = fmaxf(v1, 0.f); }
      if (row0 < N_NODES) outp[(size_t)row0 * DOUT + ct * 16 + m] = f2bits(v0);
      if (row1 < N_NODES) outp[(size_t)row1 * DOUT + ct * 16 + m] = f2bits(v1);
    }
  }
}

// ============ weight pack: fp32 [DIN x DOUT] -> bf16 B-fragment layout ============
template <int DIN, int DOUT>
__global__ __launch_bounds__(256) void k_packw(const float* __restrict__ W,
                                               short* __restrict__ o) {
  int t = blockIdx.x * 256 + threadIdx.x;
  if (t >= DIN * DOUT) return;
  constexpr int CT = DOUT / 16;
  int j = t & 7;
  int lane = (t >> 3) & 63;
  int kc = t >> 9;
  int ct = kc % CT;
  int kt = kc / CT;
  int k = kt * 32 + (lane >> 4) * 8 + j;
  int n = ct * 16 + (lane & 15);
  o[t] = (short)f2bits(W[k * DOUT + n]);
}

// ================= CSR build =================
__global__ __launch_bounds__(256) void k_hist(const int* __restrict__ dst,
                                              int* __restrict__ deg) {
  int e = blockIdx.x * 256 + threadIdx.x;
  if (e < N_EDGES) atomicAdd(&deg[dst[e]], 1);
}

__global__ __launch_bounds__(256) void k_scan_partial(const int* __restrict__ deg,
                                                      int* __restrict__ partial) {
  __shared__ int s[256];
  int i = blockIdx.x * 256 + threadIdx.x;
  s[threadIdx.x] = (i < N_NODES) ? deg[i] : 0;
  __syncthreads();
  for (int st = 128; st > 0; st >>= 1) {
    if (threadIdx.x < st) s[threadIdx.x] += s[threadIdx.x + st];
    __syncthreads();
  }
  if (threadIdx.x == 0) partial[blockIdx.x] = s[0];
}

__global__ __launch_bounds__(256) void k_scan_top(int* __restrict__ partial) {
  __shared__ int s[256];
  int t = threadIdx.x;
  int v0 = (t < SCAN_NB) ? partial[t] : 0;
  s[t] = v0;
  __syncthreads();
  for (int st = 1; st < 256; st <<= 1) {
    int v = (t >= st) ? s[t - st] : 0;
    __syncthreads();
    s[t] += v;
    __syncthreads();
  }
  if (t < SCAN_NB) partial[t] = s[t] - v0;
}

__global__ __launch_bounds__(256) void k_scan_final(const int* __restrict__ deg,
    const int* __restrict__ partial, int* __restrict__ off) {
  __shared__ int s[256];
  int i = blockIdx.x * 256 + threadIdx.x;
  int v0 = (i < N_NODES) ? deg[i] : 0;
  s[threadIdx.x] = v0;
  __syncthreads();
  for (int st = 1; st < 256; st <<= 1) {
    int v = (threadIdx.x >= st) ? s[threadIdx.x - st] : 0;
    __syncthreads();
    s[threadIdx.x] += v;
    __syncthreads();
  }
  if (i < N_NODES) off[i] = partial[blockIdx.x] + s[threadIdx.x] - v0;
  if (i == 0) off[N_NODES] = N_EDGES;
}

__global__ __launch_bounds__(256) void k_reorder(const int* __restrict__ src,
    const int* __restrict__ dst, const int* __restrict__ off,
    int* __restrict__ cur, int* __restrict__ esrc) {
  int e = blockIdx.x * 256 + threadIdx.x;
  if (e >= N_EDGES) return;
  int d = dst[e];
  int pos = off[d] + atomicAdd(&cur[d], 1);
  esrc[pos] = src[e];
}

// ============ gather: 4 nodes/wave, 16 lanes/node -> 4 indep edge streams ============
// D=128: 16 B/lane (8 bf16); D=64: 8 B/lane (4 bf16). fp32 accumulate, bf16 out.
__global__ __launch_bounds__(256) void k_gather128(const unsigned short* __restrict__ h,
    const int* __restrict__ esrc, const int* __restrict__ off,
    unsigned short* __restrict__ agg) {
  int wid = (blockIdx.x * 256 + threadIdx.x) >> 6;
  int lane = threadIdx.x & 63;
  int g = lane >> 4;
  int li = lane & 15;
  int node = wid * 4 + g;
  if (node >= N_NODES) return;
  int e = off[node], end = off[node + 1];
  int foff = li * 8;
  float a0=0.f,a1=0.f,a2=0.f,a3=0.f,a4=0.f,a5=0.f,a6=0.f,a7=0.f;
  for (; e + 2 <= end; e += 2) {
    int s0 = esrc[e], s1 = esrc[e + 1];
    uint4 va = *(const uint4*)(h + (size_t)s0 * 128 + foff);
    uint4 vb = *(const uint4*)(h + (size_t)s1 * 128 + foff);
    acc2(a0,a1,va.x); acc2(a2,a3,va.y); acc2(a4,a5,va.z); acc2(a6,a7,va.w);
    acc2(a0,a1,vb.x); acc2(a2,a3,vb.y); acc2(a4,a5,vb.z); acc2(a6,a7,vb.w);
  }
  if (e < end) {
    uint4 va = *(const uint4*)(h + (size_t)esrc[e] * 128 + foff);
    acc2(a0,a1,va.x); acc2(a2,a3,va.y); acc2(a4,a5,va.z); acc2(a6,a7,va.w);
  }
  uint4 o;
  o.x = (unsigned)f2bits(a0) | ((unsigned)f2bits(a1) << 16);
  o.y = (unsigned)f2bits(a2) | ((unsigned)f2bits(a3) << 16);
  o.z = (unsigned)f2bits(a4) | ((unsigned)f2bits(a5) << 16);
  o.w = (unsigned)f2bits(a6) | ((unsigned)f2bits(a7) << 16);
  *(uint4*)(agg + (size_t)node * 128 + foff) = o;
}

__global__ __launch_bounds__(256) void k_gather64(const unsigned short* __restrict__ h,
    const int* __restrict__ esrc, const int* __restrict__ off,
    unsigned short* __restrict__ agg) {
  int wid = (blockIdx.x * 256 + threadIdx.x) >> 6;
  int lane = threadIdx.x & 63;
  int g = lane >> 4;
  int li = lane & 15;
  int node = wid * 4 + g;
  if (node >= N_NODES) return;
  int e = off[node], end = off[node + 1];
  int foff = li * 4;
  float a0=0.f,a1=0.f,a2=0.f,a3=0.f;
  for (; e + 4 <= end; e += 4) {
    int s0 = esrc[e], s1 = esrc[e+1], s2 = esrc[e+2], s3 = esrc[e+3];
    uint2 va = *(const uint2*)(h + (size_t)s0 * 64 + foff);
    uint2 vb = *(const uint2*)(h + (size_t)s1 * 64 + foff);
    uint2 vc = *(const uint2*)(h + (size_t)s2 * 64 + foff);
    uint2 vd = *(const uint2*)(h + (size_t)s3 * 64 + foff);
    acc2(a0,a1,va.x); acc2(a2,a3,va.y);
    acc2(a0,a1,vb.x); acc2(a2,a3,vb.y);
    acc2(a0,a1,vc.x); acc2(a2,a3,vc.y);
    acc2(a0,a1,vd.x); acc2(a2,a3,vd.y);
  }
  for (; e < end; ++e) {
    uint2 va = *(const uint2*)(h + (size_t)esrc[e] * 64 + foff);
    acc2(a0,a1,va.x); acc2(a2,a3,va.y);
  }
  uint2 o;
  o.x = (unsigned)f2bits(a0) | ((unsigned)f2bits(a1) << 16);
  o.y = (unsigned)f2bits(a2) | ((unsigned)f2bits(a3) << 16);
  *(uint2*)(agg + (size_t)node * 64 + foff) = o;
}

// ================= pooling (sorted batch) =================
__device__ inline int lbound(const int* __restrict__ a, int n, int v) {
  int lo = 0, hi = n;
  while (lo < hi) {
    int m = (lo + hi) >> 1;
    if (a[m] < v) lo = m + 1; else hi = m;
  }
  return lo;
}

__global__ __launch_bounds__(128) void k_pool(const unsigned short* __restrict__ h3,
    const int* __restrict__ batch, float* __restrict__ pooled) {
  int g = blockIdx.x;
  int t = threadIdx.x;
  int lo = lbound(batch, N_NODES, g);
  int hi = lbound(batch, N_NODES, g + 1);
  float a0 = 0.f, a1 = 0.f, a2 = 0.f, a3 = 0.f;
  int r = lo;
  for (; r + 4 <= hi; r += 4) {
    a0 += bits2f(h3[(size_t)(r + 0) * OUT_CH + t]);
    a1 += bits2f(h3[(size_t)(r + 1) * OUT_CH + t]);
    a2 += bits2f(h3[(size_t)(r + 2) * OUT_CH + t]);
    a3 += bits2f(h3[(size_t)(r + 3) * OUT_CH + t]);
  }
  for (; r < hi; ++r) a0 += bits2f(h3[(size_t)r * OUT_CH + t]);
  float acc = (a0 + a1) + (a2 + a3);
  float inv = (hi > lo) ? 1.f / (float)(hi - lo) : 0.f;
  pooled[(size_t)g * OUT_CH + t] = acc * inv;
}

// ================= head (fp32) =================
__global__ __launch_bounds__(256) void k_head(const float* __restrict__ pooled,
    const float* __restrict__ lw, const float* __restrict__ lb,
    float* __restrict__ out) {
  int t = blockIdx.x * 256 + threadIdx.x;
  if (t >= NUM_G * NUM_CLS) return;
  int g = t >> 4;
  int c = t & 15;
  float s = lb[c];
#pragma unroll
  for (int k = 0; k < OUT_CH; ++k)
    s = fmaf(pooled[(size_t)g * OUT_CH + k], lw[k * NUM_CLS + c], s);
  out[t] = s;
}

extern "C" void kernel_launch(void* const* d_in, const int* in_sizes, int n_in,
                              void* d_out, int out_size, void* d_ws, size_t ws_size,
                              hipStream_t stream) {
  const float* x      = (const float*)d_in[0];
  const int*   ei     = (const int*)d_in[1];
  const int*   batch  = (const int*)d_in[2];
  const float* w1     = (const float*)d_in[4];
  const float* b1     = (const float*)d_in[5];
  const float* rel1w  = (const float*)d_in[6];
  const float* rel1b  = (const float*)d_in[7];
  const float* root1w = (const float*)d_in[8];
  const float* rel2w  = (const float*)d_in[9];
  const float* rel2b  = (const float*)d_in[10];
  const float* root2w = (const float*)d_in[11];
  const float* rel3w  = (const float*)d_in[12];
  const float* rel3b  = (const float*)d_in[13];
  const float* root3w = (const float*)d_in[14];
  const float* linw   = (const float*)d_in[15];
  const float* linb   = (const float*)d_in[16];
  const int* src = ei;
  const int* dst = ei + N_EDGES;
  float* out = (float*)d_out;

  // ---- workspace layout ----
  unsigned short* P = (unsigned short*)d_ws;            // [N,128] bf16
  unsigned short* Q = P + (size_t)N_NODES * 128;        // [N,128] bf16
  unsigned short* R = Q + (size_t)N_NODES * 128;        // [N,128] bf16
  short* WP = (short*)(R + (size_t)N_NODES * 128);
  short* w1p  = WP;                 // 128x64
  short* r1p  = w1p + 8192;         // 64x64
  short* o1p  = r1p + 4096;         // 64x64
  short* r2p  = o1p + 4096;         // 64x128
  short* o2p  = r2p + 8192;         // 64x128
  short* r3p  = o2p + 8192;         // 128x128
  short* o3p  = r3p + 16384;        // 128x128
  float* pooled = (float*)(o3p + 16384);                // [G,128] fp32
  int* deg     = (int*)(pooled + (size_t)NUM_G * OUT_CH);
  int* off     = deg + N_NODES;                         // N+1
  int* cur     = off + (N_NODES + 1);
  int* partial = cur + N_NODES;                         // 256
  int* esrc    = partial + 256;                         // [E]

  // ---- CSR build ----
  hipMemsetAsync(deg, 0, (size_t)N_NODES * sizeof(int), stream);
  hipMemsetAsync(cur, 0, (size_t)N_NODES * sizeof(int), stream);
  k_hist<<<(N_EDGES + 255) / 256, 256, 0, stream>>>(dst, deg);
  k_scan_partial<<<SCAN_NB, 256, 0, stream>>>(deg, partial);
  k_scan_top<<<1, 256, 0, stream>>>(partial);
  k_scan_final<<<SCAN_NB, 256, 0, stream>>>(deg, partial, off);
  k_reorder<<<(N_EDGES + 255) / 256, 256, 0, stream>>>(src, dst, off, cur, esrc);

  // ---- pack weights ----
  k_packw<128, 64><<<32, 256, 0, stream>>>(w1, w1p);
  k_packw<64, 64><<<16, 256, 0, stream>>>(rel1w, r1p);
  k_packw<64, 64><<<16, 256, 0, stream>>>(root1w, o1p);
  k_packw<64, 128><<<32, 256, 0, stream>>>(rel2w, r2p);
  k_packw<64, 128><<<32, 256, 0, stream>>>(root2w, o2p);
  k_packw<128, 128><<<64, 256, 0, stream>>>(rel3w, r3p);
  k_packw<128, 128><<<64, 256, 0, stream>>>(root3w, o3p);

  const int GB = (N_NODES + 127) / 128;     // 391 blocks for MFMA GEMMs
  const int GG = (N_NODES + 15) / 16;       // 3125 blocks for gathers (16 nodes/block)

  // ---- stage1 ----
  k_mfma<128, 64, false, false, true><<<GB, 256, 0, stream>>>(
      x, nullptr, w1p, nullptr, b1, P);

  // ---- layer1 ----
  k_gather64<<<GG, 256, 0, stream>>>(P, esrc, off, Q);
  k_mfma<64, 64, true, true, false><<<GB, 256, 0, stream>>>(
      Q, P, r1p, o1p, rel1b, R);

  // ---- layer2 ----
  k_gather64<<<GG, 256, 0, stream>>>(R, esrc, off, P);
  k_mfma<64, 128, true, true, false><<<GB, 256, 0, stream>>>(
      P, R, r2p, o2p, rel2b, Q);

  // ---- layer3 ----
  k_gather128<<<GG, 256, 0, stream>>>(Q, esrc, off, R);
  k_mfma<128, 128, true, true, false><<<GB, 256, 0, stream>>>(
      R, Q, r3p, o3p, rel3b, P);

  // ---- pool + head ----
  k_pool<<<NUM_G, 128, 0, stream>>>(P, batch, pooled);
  k_head<<<(NUM_G * NUM_CLS + 255) / 256, 256, 0, stream>>>(pooled, linw, linb, out);
}

// Round 6
// 289.241 us; speedup vs baseline: 5.4695x; 1.1641x over previous
//
#include <hip/hip_runtime.h>
#include <hip/hip_bf16.h>

#define N_NODES 50000
#define N_EDGES 800000
#define IN_DIM  128
#define IN_CH   64
#define HIDDEN  64
#define OUT_CH  128
#define NUM_CLS 16
#define NUM_G   512
#define SCAN_NB ((N_NODES + 255) / 256)   // 196
#define NBUK    ((N_NODES + 255) >> 8)    // 196 buckets of 256 dst nodes
#define BCAP    6144                      // mean 4082/bucket, sigma~64 -> 32-sigma margin
#define EPB_A   4096                      // edges per pass-A block

typedef __attribute__((ext_vector_type(8))) short short8;
typedef __attribute__((ext_vector_type(4))) float f32x4;

__device__ inline float bits2f(unsigned short u) {
  unsigned x = (unsigned)u << 16;
  float f;
  __builtin_memcpy(&f, &x, 4);
  return f;
}
__device__ inline unsigned short f2bits(float v) {
  __hip_bfloat16 b = __float2bfloat16(v);   // RNE
  unsigned short s;
  __builtin_memcpy(&s, &b, 2);
  return s;
}
__device__ inline short8 zero8() {
  short8 z;
#pragma unroll
  for (int i = 0; i < 8; ++i) z[i] = 0;
  return z;
}
__device__ inline void acc2(float& a0, float& a1, unsigned v) {
  a0 += bits2f((unsigned short)v);
  a1 += bits2f((unsigned short)(v >> 16));
}

// ============ MFMA GEMM: out(bf16) = [relu](A@Wa [+ H@Wh] + bias) ============
template <int DIN, int DOUT, bool ROOT, bool RELU, bool AFP32>
__global__ __launch_bounds__(256) void k_mfma(
    const void* __restrict__ Ap, const unsigned short* __restrict__ Hp,
    const short* __restrict__ Wa, const short* __restrict__ Wh,
    const float* __restrict__ bias, unsigned short* __restrict__ outp) {
  constexpr int KT = DIN / 32;
  constexpr int CT = DOUT / 16;
  const int wave = threadIdx.x >> 6;
  const int lane = threadIdx.x & 63;
  const int m = lane & 15;
  const int q = lane >> 4;
  const int rbase = blockIdx.x * 128 + wave * 32;

  short8 afr[2][KT];
  short8 hfr[2][KT];

#pragma unroll
  for (int rt = 0; rt < 2; ++rt) {
    int row = rbase + rt * 16 + m;
    bool ok = row < N_NODES;
#pragma unroll
    for (int kt = 0; kt < KT; ++kt) {
      if constexpr (AFP32) {
        short8 f = zero8();
        if (ok) {
          const float* ap = (const float*)Ap + (size_t)row * DIN + kt * 32 + q * 8;
          float4 x0 = *(const float4*)ap;
          float4 x1 = *(const float4*)(ap + 4);
          f[0] = (short)f2bits(x0.x); f[1] = (short)f2bits(x0.y);
          f[2] = (short)f2bits(x0.z); f[3] = (short)f2bits(x0.w);
          f[4] = (short)f2bits(x1.x); f[5] = (short)f2bits(x1.y);
          f[6] = (short)f2bits(x1.z); f[7] = (short)f2bits(x1.w);
        }
        afr[rt][kt] = f;
      } else {
        afr[rt][kt] = ok ? *(const short8*)((const unsigned short*)Ap +
                              (size_t)row * DIN + kt * 32 + q * 8)
                         : zero8();
      }
      if constexpr (ROOT) {
        hfr[rt][kt] = ok ? *(const short8*)(Hp + (size_t)row * DIN + kt * 32 + q * 8)
                         : zero8();
      }
    }
  }

  for (int ct = 0; ct < CT; ++ct) {
    f32x4 acc0 = {0.f, 0.f, 0.f, 0.f};
    f32x4 acc1 = {0.f, 0.f, 0.f, 0.f};
#pragma unroll
    for (int kt = 0; kt < KT; ++kt) {
      short8 b = *(const short8*)(Wa + ((size_t)(kt * CT + ct) * 64 + lane) * 8);
      acc0 = __builtin_amdgcn_mfma_f32_16x16x32_bf16(afr[0][kt], b, acc0, 0, 0, 0);
      acc1 = __builtin_amdgcn_mfma_f32_16x16x32_bf16(afr[1][kt], b, acc1, 0, 0, 0);
      if constexpr (ROOT) {
        short8 bh = *(const short8*)(Wh + ((size_t)(kt * CT + ct) * 64 + lane) * 8);
        acc0 = __builtin_amdgcn_mfma_f32_16x16x32_bf16(hfr[0][kt], bh, acc0, 0, 0, 0);
        acc1 = __builtin_amdgcn_mfma_f32_16x16x32_bf16(hfr[1][kt], bh, acc1, 0, 0, 0);
      }
    }
    float bv = bias[ct * 16 + m];
#pragma unroll
    for (int r = 0; r < 4; ++r) {
      int row0 = rbase + q * 4 + r;
      int row1 = row0 + 16;
      float v0 = acc0[r] + bv;
      float v1 = acc1[r] + bv;
      if constexpr (RELU) { v0 = fmaxf(v0, 0.f); v1 = fmaxf(v1, 0.f); }
      if (row0 < N_NODES) outp[(size_t)row0 * DOUT + ct * 16 + m] = f2bits(v0);
      if (row1 < N_NODES) outp[(size_t)row1 * DOUT + ct * 16 + m] = f2bits(v1);
    }
  }
}

// ============ weight pack: fp32 [DIN x DOUT] -> bf16 B-fragment layout ============
template <int DIN, int DOUT>
__global__ __launch_bounds__(256) void k_packw(const float* __restrict__ W,
                                               short* __restrict__ o) {
  int t = blockIdx.x * 256 + threadIdx.x;
  if (t >= DIN * DOUT) return;
  constexpr int CT = DOUT / 16;
  int j = t & 7;
  int lane = (t >> 3) & 63;
  int kc = t >> 9;
  int ct = kc % CT;
  int kt = kc / CT;
  int k = kt * 32 + (lane >> 4) * 8 + j;
  int n = ct * 16 + (lane & 15);
  o[t] = (short)f2bits(W[k * DOUT + n]);
}

// ================= bucketed CSR build =================
// Pass A: bucket edges by dst>>8 with block-local LDS histogram + bulk reserve.
__global__ __launch_bounds__(256) void k_bucketA(const int* __restrict__ src,
    const int* __restrict__ dst, int* __restrict__ bcnt, uint2* __restrict__ bbuf) {
  __shared__ int hist[NBUK], sbase[NBUK], lcur[NBUK];
  const int t = threadIdx.x;
  for (int i = t; i < NBUK; i += 256) { hist[i] = 0; lcur[i] = 0; }
  __syncthreads();
  const int e0 = blockIdx.x * EPB_A;
  int s_[16], d_[16];
  int cnt = 0;
#pragma unroll
  for (int k = 0; k < 16; ++k) {
    int e = e0 + k * 256 + t;
    if (e < N_EDGES) {
      int s = src[e], d = dst[e];
      s_[cnt] = s; d_[cnt] = d;
      atomicAdd(&hist[d >> 8], 1);
      cnt++;
    }
  }
  __syncthreads();
  for (int i = t; i < NBUK; i += 256) sbase[i] = atomicAdd(&bcnt[i], hist[i]);
  __syncthreads();
  for (int k = 0; k < cnt; ++k) {
    int b = d_[k] >> 8;
    int pos = sbase[b] + atomicAdd(&lcur[b], 1);
    if (pos < BCAP) bbuf[(size_t)b * BCAP + pos] = make_uint2((unsigned)s_[k], (unsigned)d_[k]);
  }
}

// Pass B1: per-bucket degree (dense write, no global atomics)
__global__ __launch_bounds__(256) void k_bdeg(const int* __restrict__ bcnt,
    const uint2* __restrict__ bbuf, int* __restrict__ deg) {
  __shared__ int cnt[256];
  const int b = blockIdx.x;
  cnt[threadIdx.x] = 0;
  __syncthreads();
  int n = min(bcnt[b], BCAP);
  for (int i = threadIdx.x; i < n; i += 256)
    atomicAdd(&cnt[bbuf[(size_t)b * BCAP + i].y & 255], 1);
  __syncthreads();
  int node = b * 256 + threadIdx.x;
  if (node < N_NODES) deg[node] = cnt[threadIdx.x];
}

// Pass B2: per-bucket scatter into esrc (writes land in ~16KB dense window)
__global__ __launch_bounds__(256) void k_bscatter(const int* __restrict__ bcnt,
    const uint2* __restrict__ bbuf, const int* __restrict__ off,
    int* __restrict__ esrc) {
  __shared__ int cur[256];
  __shared__ int soff[256];
  const int b = blockIdx.x;
  cur[threadIdx.x] = 0;
  int node = b * 256 + threadIdx.x;
  soff[threadIdx.x] = (node < N_NODES) ? off[node] : 0;
  __syncthreads();
  int n = min(bcnt[b], BCAP);
  for (int i = threadIdx.x; i < n; i += 256) {
    uint2 p = bbuf[(size_t)b * BCAP + i];
    int l = p.y & 255;
    int r = atomicAdd(&cur[l], 1);
    esrc[soff[l] + r] = (int)p.x;
  }
}

// ================= scan (deg -> off) =================
__global__ __launch_bounds__(256) void k_scan_partial(const int* __restrict__ deg,
                                                      int* __restrict__ partial) {
  __shared__ int s[256];
  int i = blockIdx.x * 256 + threadIdx.x;
  s[threadIdx.x] = (i < N_NODES) ? deg[i] : 0;
  __syncthreads();
  for (int st = 128; st > 0; st >>= 1) {
    if (threadIdx.x < st) s[threadIdx.x] += s[threadIdx.x + st];
    __syncthreads();
  }
  if (threadIdx.x == 0) partial[blockIdx.x] = s[0];
}

__global__ __launch_bounds__(256) void k_scan_top(int* __restrict__ partial) {
  __shared__ int s[256];
  int t = threadIdx.x;
  int v0 = (t < SCAN_NB) ? partial[t] : 0;
  s[t] = v0;
  __syncthreads();
  for (int st = 1; st < 256; st <<= 1) {
    int v = (t >= st) ? s[t - st] : 0;
    __syncthreads();
    s[t] += v;
    __syncthreads();
  }
  if (t < SCAN_NB) partial[t] = s[t] - v0;
}

__global__ __launch_bounds__(256) void k_scan_final(const int* __restrict__ deg,
    const int* __restrict__ partial, int* __restrict__ off) {
  __shared__ int s[256];
  int i = blockIdx.x * 256 + threadIdx.x;
  int v0 = (i < N_NODES) ? deg[i] : 0;
  s[threadIdx.x] = v0;
  __syncthreads();
  for (int st = 1; st < 256; st <<= 1) {
    int v = (threadIdx.x >= st) ? s[threadIdx.x - st] : 0;
    __syncthreads();
    s[threadIdx.x] += v;
    __syncthreads();
  }
  if (i < N_NODES) off[i] = partial[blockIdx.x] + s[threadIdx.x] - v0;
  if (i == 0) off[N_NODES] = N_EDGES;
}

// ============ gather: 4 nodes/wave, 16 lanes/node -> 4 indep edge streams ============
__global__ __launch_bounds__(256) void k_gather128(const unsigned short* __restrict__ h,
    const int* __restrict__ esrc, const int* __restrict__ off,
    unsigned short* __restrict__ agg) {
  int wid = (blockIdx.x * 256 + threadIdx.x) >> 6;
  int lane = threadIdx.x & 63;
  int g = lane >> 4;
  int li = lane & 15;
  int node = wid * 4 + g;
  if (node >= N_NODES) return;
  int e = off[node], end = off[node + 1];
  int foff = li * 8;
  float a0=0.f,a1=0.f,a2=0.f,a3=0.f,a4=0.f,a5=0.f,a6=0.f,a7=0.f;
  for (; e + 2 <= end; e += 2) {
    int s0 = esrc[e], s1 = esrc[e + 1];
    uint4 va = *(const uint4*)(h + (size_t)s0 * 128 + foff);
    uint4 vb = *(const uint4*)(h + (size_t)s1 * 128 + foff);
    acc2(a0,a1,va.x); acc2(a2,a3,va.y); acc2(a4,a5,va.z); acc2(a6,a7,va.w);
    acc2(a0,a1,vb.x); acc2(a2,a3,vb.y); acc2(a4,a5,vb.z); acc2(a6,a7,vb.w);
  }
  if (e < end) {
    uint4 va = *(const uint4*)(h + (size_t)esrc[e] * 128 + foff);
    acc2(a0,a1,va.x); acc2(a2,a3,va.y); acc2(a4,a5,va.z); acc2(a6,a7,va.w);
  }
  uint4 o;
  o.x = (unsigned)f2bits(a0) | ((unsigned)f2bits(a1) << 16);
  o.y = (unsigned)f2bits(a2) | ((unsigned)f2bits(a3) << 16);
  o.z = (unsigned)f2bits(a4) | ((unsigned)f2bits(a5) << 16);
  o.w = (unsigned)f2bits(a6) | ((unsigned)f2bits(a7) << 16);
  *(uint4*)(agg + (size_t)node * 128 + foff) = o;
}

__global__ __launch_bounds__(256) void k_gather64(const unsigned short* __restrict__ h,
    const int* __restrict__ esrc, const int* __restrict__ off,
    unsigned short* __restrict__ agg) {
  int wid = (blockIdx.x * 256 + threadIdx.x) >> 6;
  int lane = threadIdx.x & 63;
  int g = lane >> 4;
  int li = lane & 15;
  int node = wid * 4 + g;
  if (node >= N_NODES) return;
  int e = off[node], end = off[node + 1];
  int foff = li * 4;
  float a0=0.f,a1=0.f,a2=0.f,a3=0.f;
  for (; e + 4 <= end; e += 4) {
    int s0 = esrc[e], s1 = esrc[e+1], s2 = esrc[e+2], s3 = esrc[e+3];
    uint2 va = *(const uint2*)(h + (size_t)s0 * 64 + foff);
    uint2 vb = *(const uint2*)(h + (size_t)s1 * 64 + foff);
    uint2 vc = *(const uint2*)(h + (size_t)s2 * 64 + foff);
    uint2 vd = *(const uint2*)(h + (size_t)s3 * 64 + foff);
    acc2(a0,a1,va.x); acc2(a2,a3,va.y);
    acc2(a0,a1,vb.x); acc2(a2,a3,vb.y);
    acc2(a0,a1,vc.x); acc2(a2,a3,vc.y);
    acc2(a0,a1,vd.x); acc2(a2,a3,vd.y);
  }
  for (; e < end; ++e) {
    uint2 va = *(const uint2*)(h + (size_t)esrc[e] * 64 + foff);
    acc2(a0,a1,va.x); acc2(a2,a3,va.y);
  }
  uint2 o;
  o.x = (unsigned)f2bits(a0) | ((unsigned)f2bits(a1) << 16);
  o.y = (unsigned)f2bits(a2) | ((unsigned)f2bits(a3) << 16);
  *(uint2*)(agg + (size_t)node * 64 + foff) = o;
}

// ================= pooling (sorted batch) =================
__device__ inline int lbound(const int* __restrict__ a, int n, int v) {
  int lo = 0, hi = n;
  while (lo < hi) {
    int m = (lo + hi) >> 1;
    if (a[m] < v) lo = m + 1; else hi = m;
  }
  return lo;
}

__global__ __launch_bounds__(128) void k_pool(const unsigned short* __restrict__ h3,
    const int* __restrict__ batch, float* __restrict__ pooled) {
  int g = blockIdx.x;
  int t = threadIdx.x;
  int lo = lbound(batch, N_NODES, g);
  int hi = lbound(batch, N_NODES, g + 1);
  float a0 = 0.f, a1 = 0.f, a2 = 0.f, a3 = 0.f;
  int r = lo;
  for (; r + 4 <= hi; r += 4) {
    a0 += bits2f(h3[(size_t)(r + 0) * OUT_CH + t]);
    a1 += bits2f(h3[(size_t)(r + 1) * OUT_CH + t]);
    a2 += bits2f(h3[(size_t)(r + 2) * OUT_CH + t]);
    a3 += bits2f(h3[(size_t)(r + 3) * OUT_CH + t]);
  }
  for (; r < hi; ++r) a0 += bits2f(h3[(size_t)r * OUT_CH + t]);
  float acc = (a0 + a1) + (a2 + a3);
  float inv = (hi > lo) ? 1.f / (float)(hi - lo) : 0.f;
  pooled[(size_t)g * OUT_CH + t] = acc * inv;
}

// ================= head (fp32) =================
__global__ __launch_bounds__(256) void k_head(const float* __restrict__ pooled,
    const float* __restrict__ lw, const float* __restrict__ lb,
    float* __restrict__ out) {
  int t = blockIdx.x * 256 + threadIdx.x;
  if (t >= NUM_G * NUM_CLS) return;
  int g = t >> 4;
  int c = t & 15;
  float s = lb[c];
#pragma unroll
  for (int k = 0; k < OUT_CH; ++k)
    s = fmaf(pooled[(size_t)g * OUT_CH + k], lw[k * NUM_CLS + c], s);
  out[t] = s;
}

extern "C" void kernel_launch(void* const* d_in, const int* in_sizes, int n_in,
                              void* d_out, int out_size, void* d_ws, size_t ws_size,
                              hipStream_t stream) {
  const float* x      = (const float*)d_in[0];
  const int*   ei     = (const int*)d_in[1];
  const int*   batch  = (const int*)d_in[2];
  const float* w1     = (const float*)d_in[4];
  const float* b1     = (const float*)d_in[5];
  const float* rel1w  = (const float*)d_in[6];
  const float* rel1b  = (const float*)d_in[7];
  const float* root1w = (const float*)d_in[8];
  const float* rel2w  = (const float*)d_in[9];
  const float* rel2b  = (const float*)d_in[10];
  const float* root2w = (const float*)d_in[11];
  const float* rel3w  = (const float*)d_in[12];
  const float* rel3b  = (const float*)d_in[13];
  const float* root3w = (const float*)d_in[14];
  const float* linw   = (const float*)d_in[15];
  const float* linb   = (const float*)d_in[16];
  const int* src = ei;
  const int* dst = ei + N_EDGES;
  float* out = (float*)d_out;

  // ---- workspace layout ----
  unsigned short* P = (unsigned short*)d_ws;            // [N,128] bf16
  unsigned short* Q = P + (size_t)N_NODES * 128;        // [N,128] bf16
  unsigned short* R = Q + (size_t)N_NODES * 128;        // [N,128] bf16
  short* WP = (short*)(R + (size_t)N_NODES * 128);
  short* w1p  = WP;                 // 128x64
  short* r1p  = w1p + 8192;         // 64x64
  short* o1p  = r1p + 4096;         // 64x64
  short* r2p  = o1p + 4096;         // 64x128
  short* o2p  = r2p + 8192;         // 64x128
  short* r3p  = o2p + 8192;         // 128x128
  short* o3p  = r3p + 16384;        // 128x128
  float* pooled = (float*)(o3p + 16384);                // [G,128] fp32
  int* deg     = (int*)(pooled + (size_t)NUM_G * OUT_CH);
  int* off     = deg + N_NODES;                         // N+1
  int* partial = off + (N_NODES + 1);                   // 256
  int* bcnt    = partial + 256;                         // NBUK
  int* esrc    = bcnt + NBUK + 4;                       // [E]
  uint2* bbuf  = (uint2*)((char*)(esrc + N_EDGES) +
                          ((16 - (((size_t)(esrc + N_EDGES)) & 15)) & 15)); // [NBUK*BCAP], 16B aligned

  // ---- bucketed CSR build ----
  hipMemsetAsync(bcnt, 0, NBUK * sizeof(int), stream);
  k_bucketA<<<(N_EDGES + EPB_A - 1) / EPB_A, 256, 0, stream>>>(src, dst, bcnt, bbuf);
  k_bdeg<<<NBUK, 256, 0, stream>>>(bcnt, bbuf, deg);
  k_scan_partial<<<SCAN_NB, 256, 0, stream>>>(deg, partial);
  k_scan_top<<<1, 256, 0, stream>>>(partial);
  k_scan_final<<<SCAN_NB, 256, 0, stream>>>(deg, partial, off);
  k_bscatter<<<NBUK, 256, 0, stream>>>(bcnt, bbuf, off, esrc);

  // ---- pack weights ----
  k_packw<128, 64><<<32, 256, 0, stream>>>(w1, w1p);
  k_packw<64, 64><<<16, 256, 0, stream>>>(rel1w, r1p);
  k_packw<64, 64><<<16, 256, 0, stream>>>(root1w, o1p);
  k_packw<64, 128><<<32, 256, 0, stream>>>(rel2w, r2p);
  k_packw<64, 128><<<32, 256, 0, stream>>>(root2w, o2p);
  k_packw<128, 128><<<64, 256, 0, stream>>>(rel3w, r3p);
  k_packw<128, 128><<<64, 256, 0, stream>>>(root3w, o3p);

  const int GB = (N_NODES + 127) / 128;     // 391 blocks for MFMA GEMMs
  const int GG = (N_NODES + 15) / 16;       // gathers: 16 nodes/block

  // ---- stage1 ----
  k_mfma<128, 64, false, false, true><<<GB, 256, 0, stream>>>(
      x, nullptr, w1p, nullptr, b1, P);

  // ---- layer1 ----
  k_gather64<<<GG, 256, 0, stream>>>(P, esrc, off, Q);
  k_mfma<64, 64, true, true, false><<<GB, 256, 0, stream>>>(
      Q, P, r1p, o1p, rel1b, R);

  // ---- layer2 ----
  k_gather64<<<GG, 256, 0, stream>>>(R, esrc, off, P);
  k_mfma<64, 128, true, true, false><<<GB, 256, 0, stream>>>(
      P, R, r2p, o2p, rel2b, Q);

  // ---- layer3 ----
  k_gather128<<<GG, 256, 0, stream>>>(Q, esrc, off, R);
  k_mfma<128, 128, true, true, false><<<GB, 256, 0, stream>>>(
      R, Q, r3p, o3p, rel3b, P);

  // ---- pool + head ----
  k_pool<<<NUM_G, 128, 0, stream>>>(P, batch, pooled);
  k_head<<<(NUM_G * NUM_CLS + 255) / 256, 256, 0, stream>>>(pooled, linw, linb, out);
}

// Round 7
// 288.203 us; speedup vs baseline: 5.4892x; 1.0036x over previous
//
#include <hip/hip_runtime.h>
#include <hip/hip_bf16.h>

#define N_NODES 50000
#define N_EDGES 800000
#define IN_DIM  128
#define IN_CH   64
#define HIDDEN  64
#define OUT_CH  128
#define NUM_CLS 16
#define NUM_G   512
#define NBUK    ((N_NODES + 255) >> 8)    // 196 buckets of 256 dst nodes
#define BCAP    6144                      // mean 4082/bucket -> huge margin
#define EPB_A   4096                      // edges per pass-A block

typedef __attribute__((ext_vector_type(8))) short short8;
typedef __attribute__((ext_vector_type(4))) float f32x4;

__device__ inline float bits2f(unsigned short u) {
  unsigned x = (unsigned)u << 16;
  float f;
  __builtin_memcpy(&f, &x, 4);
  return f;
}
__device__ inline unsigned short f2bits(float v) {
  __hip_bfloat16 b = __float2bfloat16(v);   // RNE
  unsigned short s;
  __builtin_memcpy(&s, &b, 2);
  return s;
}
__device__ inline short8 zero8() {
  short8 z;
#pragma unroll
  for (int i = 0; i < 8; ++i) z[i] = 0;
  return z;
}
__device__ inline void acc2(float& a0, float& a1, unsigned v) {
  a0 += bits2f((unsigned short)v);
  a1 += bits2f((unsigned short)(v >> 16));
}
__device__ inline void accu4(float* a, uint4 v) {
  acc2(a[0], a[1], v.x); acc2(a[2], a[3], v.y);
  acc2(a[4], a[5], v.z); acc2(a[6], a[7], v.w);
}

// ============ stage1 MFMA GEMM (fp32 A input): out(bf16) = A@Wa + bias ============
__global__ __launch_bounds__(256) void k_stage1(
    const float* __restrict__ Ap, const short* __restrict__ Wa,
    const float* __restrict__ bias, unsigned short* __restrict__ outp) {
  constexpr int DIN = 128, DOUT = 64, KT = DIN / 32, CT = DOUT / 16;
  const int wave = threadIdx.x >> 6;
  const int lane = threadIdx.x & 63;
  const int m = lane & 15;
  const int q = lane >> 4;
  const int rbase = blockIdx.x * 128 + wave * 32;

  short8 afr[2][KT];
#pragma unroll
  for (int rt = 0; rt < 2; ++rt) {
    int row = rbase + rt * 16 + m;
    bool ok = row < N_NODES;
#pragma unroll
    for (int kt = 0; kt < KT; ++kt) {
      short8 f = zero8();
      if (ok) {
        const float* ap = Ap + (size_t)row * DIN + kt * 32 + q * 8;
        float4 x0 = *(const float4*)ap;
        float4 x1 = *(const float4*)(ap + 4);
        f[0] = (short)f2bits(x0.x); f[1] = (short)f2bits(x0.y);
        f[2] = (short)f2bits(x0.z); f[3] = (short)f2bits(x0.w);
        f[4] = (short)f2bits(x1.x); f[5] = (short)f2bits(x1.y);
        f[6] = (short)f2bits(x1.z); f[7] = (short)f2bits(x1.w);
      }
      afr[rt][kt] = f;
    }
  }
  for (int ct = 0; ct < CT; ++ct) {
    f32x4 acc0 = {0.f, 0.f, 0.f, 0.f};
    f32x4 acc1 = {0.f, 0.f, 0.f, 0.f};
#pragma unroll
    for (int kt = 0; kt < KT; ++kt) {
      short8 b = *(const short8*)(Wa + ((size_t)(kt * CT + ct) * 64 + lane) * 8);
      acc0 = __builtin_amdgcn_mfma_f32_16x16x32_bf16(afr[0][kt], b, acc0, 0, 0, 0);
      acc1 = __builtin_amdgcn_mfma_f32_16x16x32_bf16(afr[1][kt], b, acc1, 0, 0, 0);
    }
    float bv = bias[ct * 16 + m];
#pragma unroll
    for (int r = 0; r < 4; ++r) {
      int row0 = rbase + q * 4 + r;
      int row1 = row0 + 16;
      if (row0 < N_NODES) outp[(size_t)row0 * DOUT + ct * 16 + m] = f2bits(acc0[r] + bv);
      if (row1 < N_NODES) outp[(size_t)row1 * DOUT + ct * 16 + m] = f2bits(acc1[r] + bv);
    }
  }
}

// ============ fused gather + dual MFMA GEMM ============
// out = relu( (sum_{e} h[esrc[e]]) @ Wa + h @ Wh + bias )
// Gather builds A-fragments directly in registers: the 4 lanes sharing m=lane&15
// each accumulate feature chunks q*8 + kt*32 of node rbase+rt*16+m (16 edge
// streams per wave, KT uint4 loads per edge per lane).
template <int DIN, int DOUT>
__global__ __launch_bounds__(256) void k_fused(
    const unsigned short* __restrict__ h, const int* __restrict__ esrc,
    const int* __restrict__ off, const short* __restrict__ Wa,
    const short* __restrict__ Wh, const float* __restrict__ bias,
    unsigned short* __restrict__ outp) {
  constexpr int KT = DIN / 32;
  constexpr int CT = DOUT / 16;
  const int wave = threadIdx.x >> 6;
  const int lane = threadIdx.x & 63;
  const int m = lane & 15;
  const int q = lane >> 4;
  const int rbase = blockIdx.x * 128 + wave * 32;

  short8 afr[2][KT];
  short8 hfr[2][KT];

#pragma unroll
  for (int rt = 0; rt < 2; ++rt) {
    int node = rbase + rt * 16 + m;
    float acc[KT][8];
#pragma unroll
    for (int kt = 0; kt < KT; ++kt)
#pragma unroll
      for (int j = 0; j < 8; ++j) acc[kt][j] = 0.f;
    if (node < N_NODES) {
      int e = off[node], end = off[node + 1];
      const unsigned short* hq = h + q * 8;
      for (; e + 2 <= end; e += 2) {
        int s0 = esrc[e], s1 = esrc[e + 1];
        const unsigned short* r0 = hq + (size_t)s0 * DIN;
        const unsigned short* r1 = hq + (size_t)s1 * DIN;
#pragma unroll
        for (int kt = 0; kt < KT; ++kt) {
          uint4 va = *(const uint4*)(r0 + kt * 32);
          uint4 vb = *(const uint4*)(r1 + kt * 32);
          accu4(acc[kt], va);
          accu4(acc[kt], vb);
        }
      }
      if (e < end) {
        const unsigned short* r0 = hq + (size_t)esrc[e] * DIN;
#pragma unroll
        for (int kt = 0; kt < KT; ++kt)
          accu4(acc[kt], *(const uint4*)(r0 + kt * 32));
      }
    }
#pragma unroll
    for (int kt = 0; kt < KT; ++kt) {
      short8 f;
#pragma unroll
      for (int j = 0; j < 8; ++j) f[j] = (short)f2bits(acc[kt][j]);
      afr[rt][kt] = f;
    }
    // root operand: own row, coalesced
    bool ok = node < N_NODES;
#pragma unroll
    for (int kt = 0; kt < KT; ++kt)
      hfr[rt][kt] = ok ? *(const short8*)(h + (size_t)node * DIN + kt * 32 + q * 8)
                       : zero8();
  }

  for (int ct = 0; ct < CT; ++ct) {
    f32x4 acc0 = {0.f, 0.f, 0.f, 0.f};
    f32x4 acc1 = {0.f, 0.f, 0.f, 0.f};
#pragma unroll
    for (int kt = 0; kt < KT; ++kt) {
      short8 b = *(const short8*)(Wa + ((size_t)(kt * CT + ct) * 64 + lane) * 8);
      acc0 = __builtin_amdgcn_mfma_f32_16x16x32_bf16(afr[0][kt], b, acc0, 0, 0, 0);
      acc1 = __builtin_amdgcn_mfma_f32_16x16x32_bf16(afr[1][kt], b, acc1, 0, 0, 0);
      short8 bh = *(const short8*)(Wh + ((size_t)(kt * CT + ct) * 64 + lane) * 8);
      acc0 = __builtin_amdgcn_mfma_f32_16x16x32_bf16(hfr[0][kt], bh, acc0, 0, 0, 0);
      acc1 = __builtin_amdgcn_mfma_f32_16x16x32_bf16(hfr[1][kt], bh, acc1, 0, 0, 0);
    }
    float bv = bias[ct * 16 + m];
#pragma unroll
    for (int r = 0; r < 4; ++r) {
      int row0 = rbase + q * 4 + r;
      int row1 = row0 + 16;
      float v0 = fmaxf(acc0[r] + bv, 0.f);
      float v1 = fmaxf(acc1[r] + bv, 0.f);
      if (row0 < N_NODES) outp[(size_t)row0 * DOUT + ct * 16 + m] = f2bits(v0);
      if (row1 < N_NODES) outp[(size_t)row1 * DOUT + ct * 16 + m] = f2bits(v1);
    }
  }
}

// ============ weight pack (all 7 in one launch) ============
template <int DIN, int DOUT>
__device__ inline void pack1(const float* __restrict__ W, short* __restrict__ o,
                             int t) {
  constexpr int CT = DOUT / 16;
  int j = t & 7;
  int lane = (t >> 3) & 63;
  int kc = t >> 9;
  int ct = kc % CT;
  int kt = kc / CT;
  int k = kt * 32 + (lane >> 4) * 8 + j;
  int n = ct * 16 + (lane & 15);
  o[t] = (short)f2bits(W[k * DOUT + n]);
}

__global__ __launch_bounds__(256) void k_packall(
    const float* w1, const float* r1, const float* o1, const float* r2,
    const float* o2, const float* r3, const float* o3,
    short* w1p, short* r1p, short* o1p, short* r2p, short* o2p,
    short* r3p, short* o3p) {
  int b = blockIdx.x, t = threadIdx.x;
  if      (b < 32)  pack1<128, 64>(w1, w1p, (b - 0) * 256 + t);
  else if (b < 48)  pack1<64, 64>(r1, r1p, (b - 32) * 256 + t);
  else if (b < 64)  pack1<64, 64>(o1, o1p, (b - 48) * 256 + t);
  else if (b < 96)  pack1<64, 128>(r2, r2p, (b - 64) * 256 + t);
  else if (b < 128) pack1<64, 128>(o2, o2p, (b - 96) * 256 + t);
  else if (b < 192) pack1<128, 128>(r3, r3p, (b - 128) * 256 + t);
  else              pack1<128, 128>(o3, o3p, (b - 192) * 256 + t);
}

// ================= bucketed CSR build =================
__global__ __launch_bounds__(256) void k_bucketA(const int* __restrict__ src,
    const int* __restrict__ dst, int* __restrict__ bcnt, uint2* __restrict__ bbuf) {
  __shared__ int hist[NBUK], sbase[NBUK], lcur[NBUK];
  const int t = threadIdx.x;
  for (int i = t; i < NBUK; i += 256) { hist[i] = 0; lcur[i] = 0; }
  __syncthreads();
  const int e0 = blockIdx.x * EPB_A;
  int s_[16], d_[16];
  int cnt = 0;
#pragma unroll
  for (int k = 0; k < 16; ++k) {
    int e = e0 + k * 256 + t;
    if (e < N_EDGES) {
      s_[cnt] = src[e]; d_[cnt] = dst[e];
      atomicAdd(&hist[d_[cnt] >> 8], 1);
      cnt++;
    }
  }
  __syncthreads();
  for (int i = t; i < NBUK; i += 256) sbase[i] = atomicAdd(&bcnt[i], hist[i]);
  __syncthreads();
  for (int k = 0; k < cnt; ++k) {
    int b = d_[k] >> 8;
    int pos = sbase[b] + atomicAdd(&lcur[b], 1);
    if (pos < BCAP) bbuf[(size_t)b * BCAP + pos] = make_uint2((unsigned)s_[k], (unsigned)d_[k]);
  }
}

// exclusive scan of bucket counts -> bucket base offsets; writes off[N_NODES]
__global__ __launch_bounds__(256) void k_scanb(const int* __restrict__ bcnt,
    int* __restrict__ bbase, int* __restrict__ off) {
  __shared__ int s[256];
  int t = threadIdx.x;
  int v0 = (t < NBUK) ? min(bcnt[t], BCAP) : 0;
  s[t] = v0;
  __syncthreads();
  for (int st = 1; st < 256; st <<= 1) {
    int v = (t >= st) ? s[t - st] : 0;
    __syncthreads();
    s[t] += v;
    __syncthreads();
  }
  if (t < NBUK) bbase[t] = s[t] - v0;
  if (t == NBUK - 1) off[N_NODES] = s[t];
}

// per-bucket degree histogram + intra-bucket scan -> off[node], no global scan chain
__global__ __launch_bounds__(256) void k_bdeg2(const int* __restrict__ bcnt,
    const uint2* __restrict__ bbuf, const int* __restrict__ bbase,
    int* __restrict__ off) {
  __shared__ int cnt[256], s[256];
  const int b = blockIdx.x;
  const int t = threadIdx.x;
  cnt[t] = 0;
  __syncthreads();
  int n = min(bcnt[b], BCAP);
  for (int i = t; i < n; i += 256)
    atomicAdd(&cnt[bbuf[(size_t)b * BCAP + i].y & 255], 1);
  __syncthreads();
  int v0 = cnt[t];
  s[t] = v0;
  __syncthreads();
  for (int st = 1; st < 256; st <<= 1) {
    int v = (t >= st) ? s[t - st] : 0;
    __syncthreads();
    s[t] += v;
    __syncthreads();
  }
  int node = b * 256 + t;
  if (node < N_NODES) off[node] = bbase[b] + s[t] - v0;
}

// per-bucket scatter into esrc (dense ~16KB window per bucket)
__global__ __launch_bounds__(256) void k_bscatter(const int* __restrict__ bcnt,
    const uint2* __restrict__ bbuf, const int* __restrict__ off,
    int* __restrict__ esrc) {
  __shared__ int cur[256], soff[256];
  const int b = blockIdx.x;
  cur[threadIdx.x] = 0;
  int node = b * 256 + threadIdx.x;
  soff[threadIdx.x] = (node < N_NODES) ? off[node] : 0;
  __syncthreads();
  int n = min(bcnt[b], BCAP);
  for (int i = threadIdx.x; i < n; i += 256) {
    uint2 p = bbuf[(size_t)b * BCAP + i];
    int l = p.y & 255;
    int r = atomicAdd(&cur[l], 1);
    esrc[soff[l] + r] = (int)p.x;
  }
}

// ================= fused pool + head =================
__device__ inline int lbound(const int* __restrict__ a, int n, int v) {
  int lo = 0, hi = n;
  while (lo < hi) {
    int m = (lo + hi) >> 1;
    if (a[m] < v) lo = m + 1; else hi = m;
  }
  return lo;
}

__global__ __launch_bounds__(128) void k_poolhead(const unsigned short* __restrict__ h3,
    const int* __restrict__ batch, const float* __restrict__ lw,
    const float* __restrict__ lb, float* __restrict__ out) {
  __shared__ float sp[128];
  int g = blockIdx.x;
  int t = threadIdx.x;
  int lo = lbound(batch, N_NODES, g);
  int hi = lbound(batch, N_NODES, g + 1);
  float a0 = 0.f, a1 = 0.f, a2 = 0.f, a3 = 0.f;
  int r = lo;
  for (; r + 4 <= hi; r += 4) {
    a0 += bits2f(h3[(size_t)(r + 0) * OUT_CH + t]);
    a1 += bits2f(h3[(size_t)(r + 1) * OUT_CH + t]);
    a2 += bits2f(h3[(size_t)(r + 2) * OUT_CH + t]);
    a3 += bits2f(h3[(size_t)(r + 3) * OUT_CH + t]);
  }
  for (; r < hi; ++r) a0 += bits2f(h3[(size_t)r * OUT_CH + t]);
  float inv = (hi > lo) ? 1.f / (float)(hi - lo) : 0.f;
  sp[t] = ((a0 + a1) + (a2 + a3)) * inv;
  __syncthreads();
  if (t < NUM_CLS) {
    float s = lb[t];
#pragma unroll
    for (int k = 0; k < OUT_CH; ++k) s = fmaf(sp[k], lw[k * NUM_CLS + t], s);
    out[g * NUM_CLS + t] = s;
  }
}

extern "C" void kernel_launch(void* const* d_in, const int* in_sizes, int n_in,
                              void* d_out, int out_size, void* d_ws, size_t ws_size,
                              hipStream_t stream) {
  const float* x      = (const float*)d_in[0];
  const int*   ei     = (const int*)d_in[1];
  const int*   batch  = (const int*)d_in[2];
  const float* w1     = (const float*)d_in[4];
  const float* b1     = (const float*)d_in[5];
  const float* rel1w  = (const float*)d_in[6];
  const float* rel1b  = (const float*)d_in[7];
  const float* root1w = (const float*)d_in[8];
  const float* rel2w  = (const float*)d_in[9];
  const float* rel2b  = (const float*)d_in[10];
  const float* root2w = (const float*)d_in[11];
  const float* rel3w  = (const float*)d_in[12];
  const float* rel3b  = (const float*)d_in[13];
  const float* root3w = (const float*)d_in[14];
  const float* linw   = (const float*)d_in[15];
  const float* linb   = (const float*)d_in[16];
  const int* src = ei;
  const int* dst = ei + N_EDGES;
  float* out = (float*)d_out;

  // ---- workspace layout ----
  unsigned short* P = (unsigned short*)d_ws;            // [N,128] bf16
  unsigned short* Q = P + (size_t)N_NODES * 128;        // [N,128] bf16
  unsigned short* R = Q + (size_t)N_NODES * 128;        // [N,128] bf16
  short* WP = (short*)(R + (size_t)N_NODES * 128);
  short* w1p  = WP;                 // 128x64
  short* r1p  = w1p + 8192;         // 64x64
  short* o1p  = r1p + 4096;         // 64x64
  short* r2p  = o1p + 4096;         // 64x128
  short* o2p  = r2p + 8192;         // 64x128
  short* r3p  = o2p + 8192;         // 128x128
  short* o3p  = r3p + 16384;        // 128x128
  int* off     = (int*)(o3p + 16384);                   // N+1
  int* bcnt    = off + (N_NODES + 1);                   // NBUK
  int* bbase   = bcnt + NBUK;                           // NBUK
  int* esrc    = bbase + NBUK + 2;                      // [E]
  uint2* bbuf  = (uint2*)((char*)(esrc + N_EDGES) +
                          ((16 - (((size_t)(esrc + N_EDGES)) & 15)) & 15));

  // ---- bucketed CSR build (5 dispatches incl. memset) ----
  hipMemsetAsync(bcnt, 0, NBUK * sizeof(int), stream);
  k_bucketA<<<(N_EDGES + EPB_A - 1) / EPB_A, 256, 0, stream>>>(src, dst, bcnt, bbuf);
  k_scanb<<<1, 256, 0, stream>>>(bcnt, bbase, off);
  k_bdeg2<<<NBUK, 256, 0, stream>>>(bcnt, bbuf, bbase, off);
  k_bscatter<<<NBUK, 256, 0, stream>>>(bcnt, bbuf, off, esrc);

  // ---- weights (1 dispatch) ----
  k_packall<<<256, 256, 0, stream>>>(w1, rel1w, root1w, rel2w, root2w, rel3w,
                                     root3w, w1p, r1p, o1p, r2p, o2p, r3p, o3p);

  const int GB = (N_NODES + 127) / 128;     // 391 blocks

  // ---- pipeline: stage1 + 3 fused layers + pool/head (5 dispatches) ----
  k_stage1<<<GB, 256, 0, stream>>>(x, w1p, b1, P);
  k_fused<64, 64><<<GB, 256, 0, stream>>>(P, esrc, off, r1p, o1p, rel1b, R);
  k_fused<64, 128><<<GB, 256, 0, stream>>>(R, esrc, off, r2p, o2p, rel2b, Q);
  k_fused<128, 128><<<GB, 256, 0, stream>>>(Q, esrc, off, r3p, o3p, rel3b, P);
  k_poolhead<<<NUM_G, 128, 0, stream>>>(P, batch, linw, linb, out);
}

// Round 8
// 254.801 us; speedup vs baseline: 6.2087x; 1.1311x over previous
//
#include <hip/hip_runtime.h>
#include <hip/hip_bf16.h>

#define N_NODES 50000
#define N_EDGES 800000
#define IN_DIM  128
#define IN_CH   64
#define HIDDEN  64
#define OUT_CH  128
#define NUM_CLS 16
#define NUM_G   512
#define NBUK    ((N_NODES + 255) >> 8)    // 196 buckets of 256 dst nodes
#define BCAP    6144                      // mean 4082/bucket -> huge margin
#define EPB_A   4096                      // edges per pass-A block

typedef __attribute__((ext_vector_type(8))) short short8;
typedef __attribute__((ext_vector_type(4))) float f32x4;

__device__ inline float bits2f(unsigned short u) {
  unsigned x = (unsigned)u << 16;
  float f;
  __builtin_memcpy(&f, &x, 4);
  return f;
}
__device__ inline unsigned short f2bits(float v) {
  __hip_bfloat16 b = __float2bfloat16(v);   // RNE
  unsigned short s;
  __builtin_memcpy(&s, &b, 2);
  return s;
}
__device__ inline short8 zero8() {
  short8 z;
#pragma unroll
  for (int i = 0; i < 8; ++i) z[i] = 0;
  return z;
}
__device__ inline void acc2(float& a0, float& a1, unsigned v) {
  a0 += bits2f((unsigned short)v);
  a1 += bits2f((unsigned short)(v >> 16));
}
__device__ inline void accu4(float* a, uint4 v) {
  acc2(a[0], a[1], v.x); acc2(a[2], a[3], v.y);
  acc2(a[4], a[5], v.z); acc2(a[6], a[7], v.w);
}

// ============ stage1 MFMA GEMM (fp32 A input): out(bf16) = A@Wa + bias ============
__global__ __launch_bounds__(256) void k_stage1(
    const float* __restrict__ Ap, const short* __restrict__ Wa,
    const float* __restrict__ bias, unsigned short* __restrict__ outp) {
  constexpr int DIN = 128, DOUT = 64, KT = DIN / 32, CT = DOUT / 16;
  const int wave = threadIdx.x >> 6;
  const int lane = threadIdx.x & 63;
  const int m = lane & 15;
  const int q = lane >> 4;
  const int rbase = blockIdx.x * 128 + wave * 32;

  short8 afr[2][KT];
#pragma unroll
  for (int rt = 0; rt < 2; ++rt) {
    int row = rbase + rt * 16 + m;
    bool ok = row < N_NODES;
#pragma unroll
    for (int kt = 0; kt < KT; ++kt) {
      short8 f = zero8();
      if (ok) {
        const float* ap = Ap + (size_t)row * DIN + kt * 32 + q * 8;
        float4 x0 = *(const float4*)ap;
        float4 x1 = *(const float4*)(ap + 4);
        f[0] = (short)f2bits(x0.x); f[1] = (short)f2bits(x0.y);
        f[2] = (short)f2bits(x0.z); f[3] = (short)f2bits(x0.w);
        f[4] = (short)f2bits(x1.x); f[5] = (short)f2bits(x1.y);
        f[6] = (short)f2bits(x1.z); f[7] = (short)f2bits(x1.w);
      }
      afr[rt][kt] = f;
    }
  }
  for (int ct = 0; ct < CT; ++ct) {
    f32x4 acc0 = {0.f, 0.f, 0.f, 0.f};
    f32x4 acc1 = {0.f, 0.f, 0.f, 0.f};
#pragma unroll
    for (int kt = 0; kt < KT; ++kt) {
      short8 b = *(const short8*)(Wa + ((size_t)(kt * CT + ct) * 64 + lane) * 8);
      acc0 = __builtin_amdgcn_mfma_f32_16x16x32_bf16(afr[0][kt], b, acc0, 0, 0, 0);
      acc1 = __builtin_amdgcn_mfma_f32_16x16x32_bf16(afr[1][kt], b, acc1, 0, 0, 0);
    }
    float bv = bias[ct * 16 + m];
#pragma unroll
    for (int r = 0; r < 4; ++r) {
      int row0 = rbase + q * 4 + r;
      int row1 = row0 + 16;
      if (row0 < N_NODES) outp[(size_t)row0 * DOUT + ct * 16 + m] = f2bits(acc0[r] + bv);
      if (row1 < N_NODES) outp[(size_t)row1 * DOUT + ct * 16 + m] = f2bits(acc1[r] + bv);
    }
  }
}

// ============ fused gather + dual MFMA, ONE WAVE per 16 rows ============
// 64-thr blocks, grid=3125 -> ~12 waves/CU so the latency-bound gather has MLP.
// out = relu( (sum_e h[esrc[e]]) @ Wa + h @ Wh + bias )
template <int DIN, int DOUT>
__global__ __launch_bounds__(64) void k_fused(
    const unsigned short* __restrict__ h, const int* __restrict__ esrc,
    const int* __restrict__ off, const short* __restrict__ Wa,
    const short* __restrict__ Wh, const float* __restrict__ bias,
    unsigned short* __restrict__ outp) {
  constexpr int KT = DIN / 32;
  constexpr int CT = DOUT / 16;
  const int lane = threadIdx.x;
  const int m = lane & 15;
  const int q = lane >> 4;
  const int node = blockIdx.x * 16 + m;

  // ---- register gather: lane accumulates feature chunk q*8 + kt*32 of `node` ----
  float acc[KT][8];
#pragma unroll
  for (int kt = 0; kt < KT; ++kt)
#pragma unroll
    for (int j = 0; j < 8; ++j) acc[kt][j] = 0.f;
  if (node < N_NODES) {
    int e = off[node], end = off[node + 1];
    const unsigned short* hq = h + q * 8;
    for (; e + 2 <= end; e += 2) {
      int s0 = esrc[e], s1 = esrc[e + 1];
      const unsigned short* r0 = hq + (size_t)s0 * DIN;
      const unsigned short* r1 = hq + (size_t)s1 * DIN;
#pragma unroll
      for (int kt = 0; kt < KT; ++kt) {
        uint4 va = *(const uint4*)(r0 + kt * 32);
        uint4 vb = *(const uint4*)(r1 + kt * 32);
        accu4(acc[kt], va);
        accu4(acc[kt], vb);
      }
    }
    if (e < end) {
      const unsigned short* r0 = hq + (size_t)esrc[e] * DIN;
#pragma unroll
      for (int kt = 0; kt < KT; ++kt)
        accu4(acc[kt], *(const uint4*)(r0 + kt * 32));
    }
  }

  short8 afr[KT], hfr[KT];
#pragma unroll
  for (int kt = 0; kt < KT; ++kt) {
    short8 f;
#pragma unroll
    for (int j = 0; j < 8; ++j) f[j] = (short)f2bits(acc[kt][j]);
    afr[kt] = f;
    hfr[kt] = (node < N_NODES)
                  ? *(const short8*)(h + (size_t)node * DIN + kt * 32 + q * 8)
                  : zero8();
  }

  const int rbase = blockIdx.x * 16;
#pragma unroll
  for (int ct = 0; ct < CT; ++ct) {
    f32x4 c = {0.f, 0.f, 0.f, 0.f};
#pragma unroll
    for (int kt = 0; kt < KT; ++kt) {
      short8 b = *(const short8*)(Wa + ((size_t)(kt * CT + ct) * 64 + lane) * 8);
      c = __builtin_amdgcn_mfma_f32_16x16x32_bf16(afr[kt], b, c, 0, 0, 0);
      short8 bh = *(const short8*)(Wh + ((size_t)(kt * CT + ct) * 64 + lane) * 8);
      c = __builtin_amdgcn_mfma_f32_16x16x32_bf16(hfr[kt], bh, c, 0, 0, 0);
    }
    float bv = bias[ct * 16 + m];
#pragma unroll
    for (int r = 0; r < 4; ++r) {
      int row = rbase + q * 4 + r;
      if (row < N_NODES)
        outp[(size_t)row * DOUT + ct * 16 + m] = f2bits(fmaxf(c[r] + bv, 0.f));
    }
  }
}

// ============ weight pack (all 7 in one launch) ============
template <int DIN, int DOUT>
__device__ inline void pack1(const float* __restrict__ W, short* __restrict__ o,
                             int t) {
  constexpr int CT = DOUT / 16;
  int j = t & 7;
  int lane = (t >> 3) & 63;
  int kc = t >> 9;
  int ct = kc % CT;
  int kt = kc / CT;
  int k = kt * 32 + (lane >> 4) * 8 + j;
  int n = ct * 16 + (lane & 15);
  o[t] = (short)f2bits(W[k * DOUT + n]);
}

__global__ __launch_bounds__(256) void k_packall(
    const float* w1, const float* r1, const float* o1, const float* r2,
    const float* o2, const float* r3, const float* o3,
    short* w1p, short* r1p, short* o1p, short* r2p, short* o2p,
    short* r3p, short* o3p) {
  int b = blockIdx.x, t = threadIdx.x;
  if      (b < 32)  pack1<128, 64>(w1, w1p, (b - 0) * 256 + t);
  else if (b < 48)  pack1<64, 64>(r1, r1p, (b - 32) * 256 + t);
  else if (b < 64)  pack1<64, 64>(o1, o1p, (b - 48) * 256 + t);
  else if (b < 96)  pack1<64, 128>(r2, r2p, (b - 64) * 256 + t);
  else if (b < 128) pack1<64, 128>(o2, o2p, (b - 96) * 256 + t);
  else if (b < 192) pack1<128, 128>(r3, r3p, (b - 128) * 256 + t);
  else              pack1<128, 128>(o3, o3p, (b - 192) * 256 + t);
}

// ================= bucketed CSR build =================
__global__ __launch_bounds__(256) void k_bucketA(const int* __restrict__ src,
    const int* __restrict__ dst, int* __restrict__ bcnt, uint2* __restrict__ bbuf) {
  __shared__ int hist[NBUK], sbase[NBUK], lcur[NBUK];
  const int t = threadIdx.x;
  for (int i = t; i < NBUK; i += 256) { hist[i] = 0; lcur[i] = 0; }
  __syncthreads();
  const int e0 = blockIdx.x * EPB_A;
  int s_[16], d_[16];
  int cnt = 0;
#pragma unroll
  for (int k = 0; k < 16; ++k) {
    int e = e0 + k * 256 + t;
    if (e < N_EDGES) {
      s_[cnt] = src[e]; d_[cnt] = dst[e];
      atomicAdd(&hist[d_[cnt] >> 8], 1);
      cnt++;
    }
  }
  __syncthreads();
  for (int i = t; i < NBUK; i += 256) sbase[i] = atomicAdd(&bcnt[i], hist[i]);
  __syncthreads();
  for (int k = 0; k < cnt; ++k) {
    int b = d_[k] >> 8;
    int pos = sbase[b] + atomicAdd(&lcur[b], 1);
    if (pos < BCAP) bbuf[(size_t)b * BCAP + pos] = make_uint2((unsigned)s_[k], (unsigned)d_[k]);
  }
}

// exclusive scan of bucket counts -> bucket base offsets; writes off[N_NODES]
__global__ __launch_bounds__(256) void k_scanb(const int* __restrict__ bcnt,
    int* __restrict__ bbase, int* __restrict__ off) {
  __shared__ int s[256];
  int t = threadIdx.x;
  int v0 = (t < NBUK) ? min(bcnt[t], BCAP) : 0;
  s[t] = v0;
  __syncthreads();
  for (int st = 1; st < 256; st <<= 1) {
    int v = (t >= st) ? s[t - st] : 0;
    __syncthreads();
    s[t] += v;
    __syncthreads();
  }
  if (t < NBUK) bbase[t] = s[t] - v0;
  if (t == NBUK - 1) off[N_NODES] = s[t];
}

// per-bucket degree histogram + intra-bucket scan -> off[node]
__global__ __launch_bounds__(256) void k_bdeg2(const int* __restrict__ bcnt,
    const uint2* __restrict__ bbuf, const int* __restrict__ bbase,
    int* __restrict__ off) {
  __shared__ int cnt[256], s[256];
  const int b = blockIdx.x;
  const int t = threadIdx.x;
  cnt[t] = 0;
  __syncthreads();
  int n = min(bcnt[b], BCAP);
  for (int i = t; i < n; i += 256)
    atomicAdd(&cnt[bbuf[(size_t)b * BCAP + i].y & 255], 1);
  __syncthreads();
  int v0 = cnt[t];
  s[t] = v0;
  __syncthreads();
  for (int st = 1; st < 256; st <<= 1) {
    int v = (t >= st) ? s[t - st] : 0;
    __syncthreads();
    s[t] += v;
    __syncthreads();
  }
  int node = b * 256 + t;
  if (node < N_NODES) off[node] = bbase[b] + s[t] - v0;
}

// per-bucket scatter into esrc (dense ~16KB window per bucket)
__global__ __launch_bounds__(256) void k_bscatter(const int* __restrict__ bcnt,
    const uint2* __restrict__ bbuf, const int* __restrict__ off,
    int* __restrict__ esrc) {
  __shared__ int cur[256], soff[256];
  const int b = blockIdx.x;
  cur[threadIdx.x] = 0;
  int node = b * 256 + threadIdx.x;
  soff[threadIdx.x] = (node < N_NODES) ? off[node] : 0;
  __syncthreads();
  int n = min(bcnt[b], BCAP);
  for (int i = threadIdx.x; i < n; i += 256) {
    uint2 p = bbuf[(size_t)b * BCAP + i];
    int l = p.y & 255;
    int r = atomicAdd(&cur[l], 1);
    esrc[soff[l] + r] = (int)p.x;
  }
}

// ================= fused pool + head =================
__device__ inline int lbound(const int* __restrict__ a, int n, int v) {
  int lo = 0, hi = n;
  while (lo < hi) {
    int m = (lo + hi) >> 1;
    if (a[m] < v) lo = m + 1; else hi = m;
  }
  return lo;
}

__global__ __launch_bounds__(128) void k_poolhead(const unsigned short* __restrict__ h3,
    const int* __restrict__ batch, const float* __restrict__ lw,
    const float* __restrict__ lb, float* __restrict__ out) {
  __shared__ float sp[128];
  int g = blockIdx.x;
  int t = threadIdx.x;
  int lo = lbound(batch, N_NODES, g);
  int hi = lbound(batch, N_NODES, g + 1);
  float a0 = 0.f, a1 = 0.f, a2 = 0.f, a3 = 0.f;
  int r = lo;
  for (; r + 4 <= hi; r += 4) {
    a0 += bits2f(h3[(size_t)(r + 0) * OUT_CH + t]);
    a1 += bits2f(h3[(size_t)(r + 1) * OUT_CH + t]);
    a2 += bits2f(h3[(size_t)(r + 2) * OUT_CH + t]);
    a3 += bits2f(h3[(size_t)(r + 3) * OUT_CH + t]);
  }
  for (; r < hi; ++r) a0 += bits2f(h3[(size_t)r * OUT_CH + t]);
  float inv = (hi > lo) ? 1.f / (float)(hi - lo) : 0.f;
  sp[t] = ((a0 + a1) + (a2 + a3)) * inv;
  __syncthreads();
  if (t < NUM_CLS) {
    float s = lb[t];
#pragma unroll
    for (int k = 0; k < OUT_CH; ++k) s = fmaf(sp[k], lw[k * NUM_CLS + t], s);
    out[g * NUM_CLS + t] = s;
  }
}

extern "C" void kernel_launch(void* const* d_in, const int* in_sizes, int n_in,
                              void* d_out, int out_size, void* d_ws, size_t ws_size,
                              hipStream_t stream) {
  const float* x      = (const float*)d_in[0];
  const int*   ei     = (const int*)d_in[1];
  const int*   batch  = (const int*)d_in[2];
  const float* w1     = (const float*)d_in[4];
  const float* b1     = (const float*)d_in[5];
  const float* rel1w  = (const float*)d_in[6];
  const float* rel1b  = (const float*)d_in[7];
  const float* root1w = (const float*)d_in[8];
  const float* rel2w  = (const float*)d_in[9];
  const float* rel2b  = (const float*)d_in[10];
  const float* root2w = (const float*)d_in[11];
  const float* rel3w  = (const float*)d_in[12];
  const float* rel3b  = (const float*)d_in[13];
  const float* root3w = (const float*)d_in[14];
  const float* linw   = (const float*)d_in[15];
  const float* linb   = (const float*)d_in[16];
  const int* src = ei;
  const int* dst = ei + N_EDGES;
  float* out = (float*)d_out;

  // ---- workspace layout ----
  unsigned short* P = (unsigned short*)d_ws;            // [N,128] bf16
  unsigned short* Q = P + (size_t)N_NODES * 128;        // [N,128] bf16
  unsigned short* R = Q + (size_t)N_NODES * 128;        // [N,128] bf16
  short* WP = (short*)(R + (size_t)N_NODES * 128);
  short* w1p  = WP;                 // 128x64
  short* r1p  = w1p + 8192;         // 64x64
  short* o1p  = r1p + 4096;         // 64x64
  short* r2p  = o1p + 4096;         // 64x128
  short* o2p  = r2p + 8192;         // 64x128
  short* r3p  = o2p + 8192;         // 128x128
  short* o3p  = r3p + 16384;        // 128x128
  int* off     = (int*)(o3p + 16384);                   // N+1
  int* bcnt    = off + (N_NODES + 1);                   // NBUK
  int* bbase   = bcnt + NBUK;                           // NBUK
  int* esrc    = bbase + NBUK + 2;                      // [E]
  uint2* bbuf  = (uint2*)((char*)(esrc + N_EDGES) +
                          ((16 - (((size_t)(esrc + N_EDGES)) & 15)) & 15));

  // ---- bucketed CSR build ----
  hipMemsetAsync(bcnt, 0, NBUK * sizeof(int), stream);
  k_bucketA<<<(N_EDGES + EPB_A - 1) / EPB_A, 256, 0, stream>>>(src, dst, bcnt, bbuf);
  k_scanb<<<1, 256, 0, stream>>>(bcnt, bbase, off);
  k_bdeg2<<<NBUK, 256, 0, stream>>>(bcnt, bbuf, bbase, off);
  k_bscatter<<<NBUK, 256, 0, stream>>>(bcnt, bbuf, off, esrc);

  // ---- weights ----
  k_packall<<<256, 256, 0, stream>>>(w1, rel1w, root1w, rel2w, root2w, rel3w,
                                     root3w, w1p, r1p, o1p, r2p, o2p, r3p, o3p);

  const int GB = (N_NODES + 127) / 128;   // 391 blocks (stage1)
  const int GF = (N_NODES + 15) / 16;     // 3125 blocks (fused, 1 wave each)

  // ---- pipeline ----
  k_stage1<<<GB, 256, 0, stream>>>(x, w1p, b1, P);
  k_fused<64, 64><<<GF, 64, 0, stream>>>(P, esrc, off, r1p, o1p, rel1b, R);
  k_fused<64, 128><<<GF, 64, 0, stream>>>(R, esrc, off, r2p, o2p, rel2b, Q);
  k_fused<128, 128><<<GF, 64, 0, stream>>>(Q, esrc, off, r3p, o3p, rel3b, P);
  k_poolhead<<<NUM_G, 128, 0, stream>>>(P, batch, linw, linb, out);
}